// Round 1
// baseline (978.135 us; speedup 1.0000x reference)
//
#include <hip/hip_runtime.h>
#include <math.h>

#define NN      8192
#define LOGN    13
#define ROWS    512
#define NLEV    4
#define NNODES  31
#define EPSF    1e-6f
#define PRUNEF  0.05f
#define SQRT1_2F 0.70710678118654752f
#define TWO_PIF  6.28318530717958647692f
#define INV_PIF  0.31830988618379067f
#define HALF_PIF 1.57079632679489662f

// ---------------- reductions ----------------
__device__ __forceinline__ float blockReduceSum256(float v, float* sb) {
    int tid = threadIdx.x;
    sb[tid] = v;
    __syncthreads();
    for (int s = 128; s > 0; s >>= 1) {
        if (tid < s) sb[tid] += sb[tid + s];
        __syncthreads();
    }
    float r = sb[0];
    __syncthreads();
    return r;
}

// ---------------- in-LDS radix-2 FFT (N=8192, 256 threads) ----------------
__device__ __forceinline__ void fft_lds(float2* sh, int tid, float sgn) {
    for (int s = 1; s <= LOGN; ++s) {
        int half = 1 << (s - 1);
        int m = 1 << s;
        float invm = 1.0f / (float)m;
        for (int t = 0; t < (NN / 2) / 256; ++t) {
            int bf = tid + (t << 8);
            int grp = bf >> (s - 1);
            int j = bf & (half - 1);
            int pos = (grp << s) + j;
            float ang = sgn * TWO_PIF * (float)j * invm;
            float sw, cw;
            sincosf(ang, &sw, &cw);
            float2 a = sh[pos];
            float2 b = sh[pos + half];
            float tr = cw * b.x - sw * b.y;
            float ti = cw * b.y + sw * b.x;
            sh[pos]        = make_float2(a.x + tr, a.y + ti);
            sh[pos + half] = make_float2(a.x - tr, a.y - ti);
        }
        __syncthreads();
    }
}

// ---------------- K1: FFT + frequency filter + per-row gpu ----------------
__global__ __launch_bounds__(256) void k_fft_filter(
    const float* __restrict__ x, float2* __restrict__ lev0, float2* __restrict__ gpuv,
    const float* lfg_p, const float* sig_p, const float* hfg_p, const float* cut_p)
{
    __shared__ float2 sh[NN];   // 64KB
    int row = blockIdx.x, tid = threadIdx.x;
    const float* xr = x + ((size_t)row << LOGN);
    for (int t = 0; t < NN / 256; ++t) {
        int i = tid + (t << 8);
        int r = __brev((unsigned)i) >> (32 - LOGN);
        sh[r] = make_float2(xr[i], 0.f);
    }
    __syncthreads();
    fft_lds(sh, tid, -1.f);

    float lfg = *lfg_p, sigma = *sig_p, hfg = *hfg_p, cutoff = *cut_p;
    float gs = fmaxf(sigma, 0.05f);
    float is2 = 1.f / (sigma * sigma);
    float sux = 0.f, suy = 0.f;
    float2* o = lev0 + ((size_t)row << LOGN);
    for (int t = 0; t < NN / 256; ++t) {
        int k = tid + (t << 8);
        float fk = (k < NN / 2) ? (float)k : (float)(k - NN);
        float f = fk * (1.0f / (float)NN);
        float r2 = f * f;
        float lfb = 1.f + lfg * expf(-r2 * is2);
        float radius = sqrtf(r2 + 1e-12f);
        float gate = 1.f / (1.f + expf(-(cutoff - radius) / gs));
        float mult = lfb * (hfg + (1.f - hfg) * gate);
        float2 c = sh[k];
        c.x *= mult; c.y *= mult;
        o[k] = c;
        float m = sqrtf(c.x * c.x + c.y * c.y);
        float inv = 1.f / fmaxf(m, EPSF);
        sux += c.x * inv; suy += c.y * inv;
    }
    __syncthreads();                 // done reading sh; reuse as reduce scratch
    float* sb = (float*)sh;
    sux = blockReduceSum256(sux, sb);
    suy = blockReduceSum256(suy, sb);
    if (tid == 0) {
        float gx = sux / (float)NN, gy = suy / (float)NN;
        float ga = sqrtf(gx * gx + gy * gy);
        float im = 1.f / fmaxf(ga, EPSF);
        gpuv[row] = make_float2(gx * im, gy * im);
    }
}

// ---------------- K2: one Haar level (parent width ndp -> children) --------
__global__ __launch_bounds__(256) void k_haar(
    const float2* __restrict__ src, float2* __restrict__ dst, int ndp, int lognh)
{
    size_t idx = (size_t)blockIdx.x * 256 + threadIdx.x;
    if (idx >= (size_t)ROWS * NN) return;
    int row = (int)(idx >> LOGN);
    int j = (int)(idx & (NN - 1));
    int cnode = j >> lognh;
    int i = j & ((1 << lognh) - 1);
    int pnode = cnode >> 1;
    int hi = cnode & 1;
    const float2* p = src + ((size_t)row << LOGN) + (size_t)pnode * ndp + 2 * i;
    float2 e = p[0], o = p[1];
    float2 v;
    if (!hi) { v.x = (e.x + o.x) * SQRT1_2F; v.y = (e.y + o.y) * SQRT1_2F; }
    else     { v.x = (e.x - o.x) * SQRT1_2F; v.y = (e.y - o.y) * SQRT1_2F; }
    dst[idx] = v;
}

// ---------------- K3: per-(node,row) stats: energy, coherence, entropy -----
__global__ __launch_bounds__(256) void k_stats(
    const float2* __restrict__ lev, int depth, const float2* __restrict__ gpuv,
    float* __restrict__ Se, float* __restrict__ Coh, float* __restrict__ Ent)
{
    int nodes = 1 << depth;
    int nd = NN >> depth;
    int node = blockIdx.x & (nodes - 1);
    int row = blockIdx.x >> depth;
    int g = (nodes - 1) + node;
    const float2* c = lev + ((size_t)row << LOGN) + (size_t)node * nd;
    __shared__ float sb[256];
    int tid = threadIdx.x;

    float se = 0.f, sux = 0.f, suy = 0.f;
    for (int i = tid; i < nd; i += 256) {
        float2 v = c[i];
        float e = v.x * v.x + v.y * v.y;
        se += e;
        float inv = 1.f / fmaxf(sqrtf(e), EPSF);
        sux += v.x * inv; suy += v.y * inv;
    }
    se = blockReduceSum256(se, sb);
    sux = blockReduceSum256(sux, sb);
    suy = blockReduceSum256(suy, sb);

    float denom = fmaxf(se, EPSF);
    float ent = 0.f;
    for (int i = tid; i < nd; i += 256) {
        float2 v = c[i];
        float e = v.x * v.x + v.y * v.y;
        float p = fmaxf(e / denom, EPSF);
        ent += -p * logf(p);
    }
    ent = blockReduceSum256(ent, sb);

    if (tid == 0) {
        float2 gp = gpuv[row];
        float zx = sux / (float)nd, zy = suy / (float)nd;
        float wr = zx * gp.x + zy * gp.y;      // Re(z * conj(gpu))
        float wi = zy * gp.x - zx * gp.y;      // Im(z * conj(gpu))
        float ch = fminf(sqrtf(wr * wr + wi * wi), 1.f);
        Se[g * ROWS + row] = se;
        Coh[g * ROWS + row] = ch;
        Ent[g * ROWS + row] = ent;
    }
}

// ---------------- K4: scalar decisions (costs, sel, frontier, prune) -------
__global__ __launch_bounds__(256) void k_decide(
    const float* __restrict__ Se, const float* __restrict__ Coh, const float* __restrict__ Ent,
    int* __restrict__ frontier, int* __restrict__ mergeact, int* __restrict__ pruneF)
{
    __shared__ float sb[256];
    __shared__ float cost[NNODES], ne[NNODES], cm[NNODES];
    int tid = threadIdx.x;
    for (int gn = 0; gn < NNODES; ++gn) {
        float a = 0.f, b = 0.f, cc = 0.f;
        for (int r = tid; r < ROWS; r += 256) {
            float e = Ent[gn * ROWS + r], ch = Coh[gn * ROWS + r];
            a += e + 1.f - ch;
            b += Se[gn * ROWS + r];
            cc += ch;
        }
        a = blockReduceSum256(a, sb);
        b = blockReduceSum256(b, sb);
        cc = blockReduceSum256(cc, sb);
        if (tid == 0) { cost[gn] = a / (float)ROWS; ne[gn] = b; cm[gn] = cc / (float)ROWS; }
        __syncthreads();
    }
    if (tid == 0) {
        float mc[NNODES]; int sel[NNODES]; int act[NNODES];
        for (int gn = NNODES - 1; gn >= 0; --gn) {
            if (gn >= 15) { mc[gn] = cost[gn]; sel[gn] = 0; }
            else {
                float chc = mc[2 * gn + 1] + mc[2 * gn + 2];
                sel[gn] = (chc < cost[gn]) ? 1 : 0;
                mc[gn] = fminf(chc, cost[gn]);
            }
        }
        float total_e = ne[0];
        act[0] = 1;
        for (int gn = 1; gn < NNODES; ++gn) {
            int p = (gn - 1) >> 1;
            act[gn] = act[p] && sel[p];
        }
        for (int gn = 0; gn < NNODES; ++gn) {
            int isleaf = (gn >= 15);
            frontier[gn] = (act[gn] && (isleaf || !sel[gn])) ? 1 : 0;
            mergeact[gn] = (act[gn] && sel[gn] && !isleaf) ? 1 : 0;
            pruneF[gn] = ((ne[gn] / total_e < PRUNEF) || (cm[gn] < PRUNEF)) ? 1 : 0;
        }
    }
}

// ---------------- leaf filter per-element (MLP gain) -----------------------
// w layout in LDS: Wp[0..83], bp[84..95], Wo row0 [96..107], Wo row1 [108..119], bo[120..121]
__device__ __forceinline__ void leaf_filtered(
    float2 cv, float nle, float dn, float bcv, float coh, float pos,
    const float* w, float gbase, float& fr, float& fi)
{
    float mag = fmaxf(sqrtf(cv.x * cv.x + cv.y * cv.y), EPSF);
    float f[7];
    f[0] = logf(mag);
    f[1] = atan2f(cv.y, cv.x) * INV_PIF;
    f[2] = nle; f[3] = dn; f[4] = bcv; f[5] = coh; f[6] = pos;
    float acc0 = w[120], acc1 = w[121];
    #pragma unroll
    for (int j = 0; j < 12; ++j) {
        float h = w[84 + j];
        #pragma unroll
        for (int k = 0; k < 7; ++k) h = fmaf(f[k], w[j * 7 + k], h);
        float s = h / (1.f + expf(-h));          // silu
        acc0 = fmaf(s, w[96 + j], acc0);
        acc1 = fmaf(s, w[108 + j], acc1);
    }
    float gm = gbase * expf(0.25f * tanhf(acc0));
    float dp = HALF_PIF * tanhf(acc1);
    float sp, cp;
    sincosf(dp, &sp, &cp);
    float gr = gm * cp, gi = gm * sp;
    fr = cv.x * gr - cv.y * gi;
    fi = cv.x * gi + cv.y * gr;
}

// ---------------- K5: frontier-node leaf filter (MLP + bitonic median) -----
__global__ __launch_bounds__(256) void k_filter(
    const float2* __restrict__ lev, int depth,
    const float* __restrict__ Se, const float* __restrict__ Coh,
    const int* __restrict__ frontier, const int* __restrict__ pruneF,
    float2* __restrict__ outS,
    const float* __restrict__ Wp, const float* __restrict__ bp,
    const float* __restrict__ Wo, const float* __restrict__ bo,
    const float* lfg_p, const float* sig_p, const float* hfg_p, const float* cut_p)
{
    int nodes = 1 << depth;
    int nd = NN >> depth;
    int node = blockIdx.x & (nodes - 1);
    int row = blockIdx.x >> depth;
    int g = (nodes - 1) + node;
    if (!frontier[g]) return;

    __shared__ float sortb[NN];    // 32KB
    __shared__ float wsh[122];
    int tid = threadIdx.x;
    if (tid < 84) wsh[tid] = Wp[tid];
    else if (tid < 96) wsh[tid] = bp[tid - 84];
    else if (tid < 120) wsh[tid] = Wo[tid - 96];
    else if (tid < 122) wsh[tid] = bo[tid - 120];
    __syncthreads();

    float lfg = *lfg_p, sigma = *sig_p, hfg = *hfg_p, cutoff = *cut_p;
    float bcv = (depth == 0) ? 0.f : ((float)node + 0.5f) / (float)nodes;
    float coh = Coh[g * ROWS + row];
    float se  = Se[g * ROWS + row];
    float nle = logf(fmaxf(se / (float)nd, EPSF));
    float dn = (float)depth / (float)NLEV;
    float lbb = 1.f + lfg * expf(-(bcv * bcv) / (sigma * sigma));
    float hbd = hfg + (1.f - hfg) * (1.f / (1.f + expf(-(cutoff - bcv) / sigma)));
    float gbase = lbb * hbd * (1.f + lfg * coh) * (hfg + (1.f - hfg) * coh);
    float invnm1 = 1.f / (float)(nd - 1);

    const float2* c = lev + ((size_t)row << LOGN) + (size_t)node * nd;

    // pass A: |filtered| into LDS for median
    for (int i = tid; i < nd; i += 256) {
        float fr, fi;
        leaf_filtered(c[i], nle, dn, bcv, coh, (float)i * invnm1, wsh, gbase, fr, fi);
        sortb[i] = sqrtf(fr * fr + fi * fi);
    }
    __syncthreads();
    // bitonic sort ascending
    for (int kk = 2; kk <= nd; kk <<= 1) {
        for (int jj = kk >> 1; jj > 0; jj >>= 1) {
            for (int i = tid; i < nd; i += 256) {
                int l = i ^ jj;
                if (l > i) {
                    float a = sortb[i], b = sortb[l];
                    bool up = ((i & kk) == 0);
                    bool sw = up ? (a > b) : (a < b);
                    if (sw) { sortb[i] = b; sortb[l] = a; }
                }
            }
            __syncthreads();
        }
    }
    float nf = 0.5f * (sortb[nd / 2 - 1] + sortb[nd / 2]);
    float thr = (1.f - hbd) * nf;                      // (1-damping)*median
    float pf = pruneF[g] ? (hfg * hfg) : 1.f;

    float2* o = outS + ((size_t)row << LOGN) + (size_t)node * nd;
    // pass B: recompute filtered, soft-threshold magnitude, prune scale
    for (int i = tid; i < nd; i += 256) {
        float fr, fi;
        leaf_filtered(c[i], nle, dn, bcv, coh, (float)i * invnm1, wsh, gbase, fr, fi);
        float fm = sqrtf(fr * fr + fi * fi);
        float den = fmaxf(fm - thr, 0.f);
        float s = den / fmaxf(fm, EPSF) * pf;
        o[i] = make_float2(fr * s, fi * s);
    }
}

// ---------------- K6: bottom-up Haar merge in place ------------------------
__global__ __launch_bounds__(256) void k_merge(
    float2* __restrict__ outS, int pdepth, const int* __restrict__ mergeact)
{
    int nodes = 1 << pdepth;
    int nd = NN >> pdepth;
    int node = blockIdx.x & (nodes - 1);
    int row = blockIdx.x >> pdepth;
    int g = (nodes - 1) + node;
    if (!mergeact[g]) return;

    __shared__ float2 sh[NN];  // 64KB worst case (pdepth=0)
    int tid = threadIdx.x;
    float2* base = outS + ((size_t)row << LOGN) + (size_t)node * nd;
    for (int i = tid; i < nd; i += 256) sh[i] = base[i];
    __syncthreads();
    int nh = nd >> 1;
    for (int i = tid; i < nh; i += 256) {
        float2 lo = sh[i], hi = sh[nh + i];
        float2 ev, od;
        ev.x = (lo.x + hi.x) * SQRT1_2F; ev.y = (lo.y + hi.y) * SQRT1_2F;
        od.x = (lo.x - hi.x) * SQRT1_2F; od.y = (lo.y - hi.y) * SQRT1_2F;
        base[2 * i]     = ev;
        base[2 * i + 1] = od;
    }
}

// ---------------- K7: IFFT + real part -------------------------------------
__global__ __launch_bounds__(256) void k_ifft(
    const float2* __restrict__ outS, float* __restrict__ out)
{
    __shared__ float2 sh[NN];
    int row = blockIdx.x, tid = threadIdx.x;
    const float2* sr = outS + ((size_t)row << LOGN);
    for (int t = 0; t < NN / 256; ++t) {
        int i = tid + (t << 8);
        int r = __brev((unsigned)i) >> (32 - LOGN);
        sh[r] = sr[i];
    }
    __syncthreads();
    fft_lds(sh, tid, +1.f);
    float* orow = out + ((size_t)row << LOGN);
    for (int t = 0; t < NN / 256; ++t) {
        int k = tid + (t << 8);
        orow[k] = sh[k].x * (1.0f / (float)NN);
    }
}

// ---------------- host launch ----------------------------------------------
extern "C" void kernel_launch(void* const* d_in, const int* in_sizes, int n_in,
                              void* d_out, int out_size, void* d_ws, size_t ws_size,
                              hipStream_t stream) {
    const float* x   = (const float*)d_in[0];
    const float* Wp  = (const float*)d_in[1];
    const float* bp  = (const float*)d_in[2];
    const float* Wo  = (const float*)d_in[3];
    const float* bo  = (const float*)d_in[4];
    const float* lfg = (const float*)d_in[5];
    const float* sig = (const float*)d_in[6];
    const float* hfg = (const float*)d_in[7];
    const float* cut = (const float*)d_in[8];
    float* out = (float*)d_out;

    size_t S = (size_t)ROWS * NN * sizeof(float2);   // 33,554,432 B
    char* ws = (char*)d_ws;
    float2* levA = (float2*)(ws);
    float2* levB = (float2*)(ws + S);
    float2* outS = (float2*)(ws + 2 * S);
    float*  Se   = (float*)(ws + 3 * S);
    float*  Coh  = Se  + (size_t)NNODES * ROWS;
    float*  Ent  = Coh + (size_t)NNODES * ROWS;
    float2* gpuv = (float2*)(Ent + (size_t)NNODES * ROWS);
    int* frontier = (int*)(gpuv + ROWS);
    int* mergeact = frontier + NNODES;
    int* pruneF   = mergeact + NNODES;
    size_t need = (size_t)((char*)(pruneF + NNODES) - ws);
    if (ws_size < need) return;   // insufficient scratch: bail (output stays invalid)

    dim3 b(256);
    int haar_grid = (ROWS * NN) / 256;   // 16384

    // ---- phase 1: stats over all 31 nodes + decisions ----
    k_fft_filter<<<dim3(ROWS), b, 0, stream>>>(x, levA, gpuv, lfg, sig, hfg, cut);
    k_stats<<<dim3(ROWS << 0), b, 0, stream>>>(levA, 0, gpuv, Se, Coh, Ent);
    k_haar<<<dim3(haar_grid), b, 0, stream>>>(levA, levB, NN, LOGN - 1);
    k_stats<<<dim3(ROWS << 1), b, 0, stream>>>(levB, 1, gpuv, Se, Coh, Ent);
    k_haar<<<dim3(haar_grid), b, 0, stream>>>(levB, levA, NN >> 1, LOGN - 2);
    k_stats<<<dim3(ROWS << 2), b, 0, stream>>>(levA, 2, gpuv, Se, Coh, Ent);
    k_haar<<<dim3(haar_grid), b, 0, stream>>>(levA, levB, NN >> 2, LOGN - 3);
    k_stats<<<dim3(ROWS << 3), b, 0, stream>>>(levB, 3, gpuv, Se, Coh, Ent);
    k_haar<<<dim3(haar_grid), b, 0, stream>>>(levB, levA, NN >> 3, LOGN - 4);
    k_stats<<<dim3(ROWS << 4), b, 0, stream>>>(levA, 4, gpuv, Se, Coh, Ent);
    k_decide<<<dim3(1), b, 0, stream>>>(Se, Coh, Ent, frontier, mergeact, pruneF);

    // ---- phase 2: regenerate levels, filter frontier, merge, ifft ----
    k_fft_filter<<<dim3(ROWS), b, 0, stream>>>(x, levA, gpuv, lfg, sig, hfg, cut);
    k_filter<<<dim3(ROWS << 0), b, 0, stream>>>(levA, 0, Se, Coh, frontier, pruneF, outS, Wp, bp, Wo, bo, lfg, sig, hfg, cut);
    k_haar<<<dim3(haar_grid), b, 0, stream>>>(levA, levB, NN, LOGN - 1);
    k_filter<<<dim3(ROWS << 1), b, 0, stream>>>(levB, 1, Se, Coh, frontier, pruneF, outS, Wp, bp, Wo, bo, lfg, sig, hfg, cut);
    k_haar<<<dim3(haar_grid), b, 0, stream>>>(levB, levA, NN >> 1, LOGN - 2);
    k_filter<<<dim3(ROWS << 2), b, 0, stream>>>(levA, 2, Se, Coh, frontier, pruneF, outS, Wp, bp, Wo, bo, lfg, sig, hfg, cut);
    k_haar<<<dim3(haar_grid), b, 0, stream>>>(levA, levB, NN >> 2, LOGN - 3);
    k_filter<<<dim3(ROWS << 3), b, 0, stream>>>(levB, 3, Se, Coh, frontier, pruneF, outS, Wp, bp, Wo, bo, lfg, sig, hfg, cut);
    k_haar<<<dim3(haar_grid), b, 0, stream>>>(levB, levA, NN >> 3, LOGN - 4);
    k_filter<<<dim3(ROWS << 4), b, 0, stream>>>(levA, 4, Se, Coh, frontier, pruneF, outS, Wp, bp, Wo, bo, lfg, sig, hfg, cut);

    k_merge<<<dim3(ROWS << 3), b, 0, stream>>>(outS, 3, mergeact);
    k_merge<<<dim3(ROWS << 2), b, 0, stream>>>(outS, 2, mergeact);
    k_merge<<<dim3(ROWS << 1), b, 0, stream>>>(outS, 1, mergeact);
    k_merge<<<dim3(ROWS << 0), b, 0, stream>>>(outS, 0, mergeact);

    k_ifft<<<dim3(ROWS), b, 0, stream>>>(outS, out);
}

// Round 2
// 283.483 us; speedup vs baseline: 3.4504x; 3.4504x over previous
//
#include <hip/hip_runtime.h>
#include <math.h>

#define NN      8192
#define LOGN    13
#define ROWS    512
#define NLEV    4
#define NNODES  31
#define EPSF    1e-6f
#define PRUNEF  0.05f
#define SQRT1_2F 0.70710678118654752f
#define TWO_PIF  6.28318530717958647692f
#define INV_PIF  0.31830988618379067f
#define HALF_PIF 1.57079632679489662f

typedef unsigned int uint;

// ---------------- fast math helpers ----------------
__device__ __forceinline__ float fast_rcp(float x)  { return __builtin_amdgcn_rcpf(x); }
__device__ __forceinline__ float fast_rsq(float x)  { return __builtin_amdgcn_rsqf(x); }

__device__ __forceinline__ float tanh_fast(float x) {
    float e = __expf(2.f * x);
    return 1.f - 2.f * fast_rcp(e + 1.f);
}

// atan2 via Cephes-style poly, ~1e-6 abs accuracy
__device__ __forceinline__ float fast_atan2f(float y, float x) {
    float ay = fabsf(y), ax = fabsf(x);
    float mx = fmaxf(ax, ay), mn = fminf(ax, ay);
    float a = (mx > 0.f) ? (mn * fast_rcp(mx)) : 0.f;      // [0,1]
    bool big = a > 0.4142135679f;
    float t = big ? ((a - 1.f) * fast_rcp(a + 1.f)) : a;
    float z2 = t * t;
    float p = fmaf(8.05374449538e-2f, z2, -1.38776856032e-1f);
    p = fmaf(p, z2, 1.99777106478e-1f);
    p = fmaf(p, z2, -3.33329491539e-1f);
    float r = fmaf(p * z2, t, t);
    if (big) r += 0.78539816339744831f;
    if (ay > ax) r = 1.57079632679489662f - r;
    if (x < 0.f) r = 3.14159265358979323f - r;
    return copysignf(r, y);
}

// ---------------- in-LDS radix-2 FFT (N=8192, 256 threads) ----------------
__device__ __forceinline__ void fft_lds(float2* sh, int tid, float sgn) {
    for (int s = 1; s <= LOGN; ++s) {
        int half = 1 << (s - 1);
        float invm = 1.0f / (float)(1 << s);
        #pragma unroll
        for (int t = 0; t < (NN / 2) / 256; ++t) {
            int bf = tid + (t << 8);
            int j = bf & (half - 1);
            int pos = ((bf >> (s - 1)) << s) + j;
            float ang = sgn * TWO_PIF * (float)j * invm;
            float sw = __sinf(ang);
            float cw = __cosf(ang);
            float2 a = sh[pos];
            float2 b = sh[pos + half];
            float tr = cw * b.x - sw * b.y;
            float ti = cw * b.y + sw * b.x;
            sh[pos]        = make_float2(a.x + tr, a.y + ti);
            sh[pos + half] = make_float2(a.x - tr, a.y - ti);
        }
        __syncthreads();
    }
}

// ---------------- K1: FFT + frequency filter + per-row gpu ----------------
__global__ __launch_bounds__(256) void k_fft_filter(
    const float* __restrict__ x, float2* __restrict__ lev0, float2* __restrict__ gpuv,
    const float* lfg_p, const float* sig_p, const float* hfg_p, const float* cut_p)
{
    __shared__ float2 sh[NN];   // 64KB
    int row = blockIdx.x, tid = threadIdx.x;
    const float* xr = x + ((size_t)row << LOGN);
    #pragma unroll
    for (int t = 0; t < NN / 256; ++t) {
        int i = tid + (t << 8);
        int r = __brev((uint)i) >> (32 - LOGN);
        sh[r] = make_float2(xr[i], 0.f);
    }
    __syncthreads();
    fft_lds(sh, tid, -1.f);

    float lfg = *lfg_p, sigma = *sig_p, hfg = *hfg_p, cutoff = *cut_p;
    float inv_gs = 1.f / fmaxf(sigma, 0.05f);
    float is2 = 1.f / (sigma * sigma);
    float sux = 0.f, suy = 0.f;
    float2* o = lev0 + ((size_t)row << LOGN);
    #pragma unroll
    for (int t = 0; t < NN / 256; ++t) {
        int k = tid + (t << 8);
        float fk = (k < NN / 2) ? (float)k : (float)(k - NN);
        float f = fk * (1.0f / (float)NN);
        float r2 = f * f;
        float lfb = 1.f + lfg * __expf(-r2 * is2);
        float radius = sqrtf(r2 + 1e-12f);
        float gate = fast_rcp(1.f + __expf(-(cutoff - radius) * inv_gs));
        float mult = lfb * (hfg + (1.f - hfg) * gate);
        float2 c = sh[k];
        c.x *= mult; c.y *= mult;
        o[k] = c;
        float m2 = c.x * c.x + c.y * c.y;
        float inv = fminf(fast_rsq(m2), 1e6f);      // == 1/max(|c|,1e-6)
        sux += c.x * inv; suy += c.y * inv;
    }
    __syncthreads();                 // done reading sh; reuse as reduce scratch
    float2* sb2 = (float2*)sh;
    sb2[tid] = make_float2(sux, suy);
    __syncthreads();
    for (int s = 128; s > 0; s >>= 1) {
        if (tid < s) { sb2[tid].x += sb2[tid + s].x; sb2[tid].y += sb2[tid + s].y; }
        __syncthreads();
    }
    if (tid == 0) {
        float gx = sb2[0].x / (float)NN, gy = sb2[0].y / (float)NN;
        float ga = sqrtf(gx * gx + gy * gy);
        float im = 1.f / fmaxf(ga, EPSF);
        gpuv[row] = make_float2(gx * im, gy * im);
    }
}

// ---------------- K2: one Haar level, pair-read (read once, write both) ----
__global__ __launch_bounds__(256) void k_haar(
    const float2* __restrict__ src, float2* __restrict__ dst, int ndp, int lognh)
{
    size_t idx = (size_t)blockIdx.x * 256 + threadIdx.x;
    if (idx >= (size_t)ROWS * (NN / 2)) return;
    int row = (int)(idx >> (LOGN - 1));
    int j = (int)(idx & (NN / 2 - 1));
    int p = j >> lognh;                    // parent node
    int i = j & ((1 << lognh) - 1);        // pair index within parent
    size_t rb = ((size_t)row << LOGN);
    size_t soff = rb + (size_t)p * ndp + 2 * i;
    float4 pr = *reinterpret_cast<const float4*>(src + soff);   // (even, odd)
    float2 lo, hi;
    lo.x = (pr.x + pr.z) * SQRT1_2F; lo.y = (pr.y + pr.w) * SQRT1_2F;
    hi.x = (pr.x - pr.z) * SQRT1_2F; hi.y = (pr.y - pr.w) * SQRT1_2F;
    size_t doff = rb + (size_t)p * ndp + i;      // low child start == parent start
    dst[doff] = lo;
    dst[doff + (1 << lognh)] = hi;
}

// ---------------- K3: per-(node,row) stats single-pass ---------------------
// ent = log(E) - (sum e*log e)/E   (entropy only feeds scalar decisions)
__global__ __launch_bounds__(256) void k_stats(
    const float2* __restrict__ lev, int depth, const float2* __restrict__ gpuv,
    float* __restrict__ Se, float* __restrict__ Coh, float* __restrict__ Ent)
{
    int nodes = 1 << depth;
    int nd = NN >> depth;
    int node = blockIdx.x & (nodes - 1);
    int row = blockIdx.x >> depth;
    int g = (nodes - 1) + node;
    const float4* c4 = reinterpret_cast<const float4*>(
        lev + ((size_t)row << LOGN) + (size_t)node * nd);
    __shared__ float4 sb4[256];
    int tid = threadIdx.x;

    float se = 0.f, sel = 0.f, sux = 0.f, suy = 0.f;
    for (int i = tid; i < nd / 2; i += 256) {
        float4 v = c4[i];
        float e1 = v.x * v.x + v.y * v.y;
        float e2 = v.z * v.z + v.w * v.w;
        se += e1 + e2;
        sel += e1 * __logf(fmaxf(e1, 1e-30f)) + e2 * __logf(fmaxf(e2, 1e-30f));
        float i1 = fminf(fast_rsq(e1), 1e6f);
        float i2 = fminf(fast_rsq(e2), 1e6f);
        sux += v.x * i1 + v.z * i2;
        suy += v.y * i1 + v.w * i2;
    }
    sb4[tid] = make_float4(se, sel, sux, suy);
    __syncthreads();
    for (int s = 128; s > 0; s >>= 1) {
        if (tid < s) {
            sb4[tid].x += sb4[tid + s].x; sb4[tid].y += sb4[tid + s].y;
            sb4[tid].z += sb4[tid + s].z; sb4[tid].w += sb4[tid + s].w;
        }
        __syncthreads();
    }
    if (tid == 0) {
        float4 r = sb4[0];
        float denom = fmaxf(r.x, EPSF);
        float ent = __logf(denom) - r.y / denom;
        float2 gp = gpuv[row];
        float zx = r.z / (float)nd, zy = r.w / (float)nd;
        float wr = zx * gp.x + zy * gp.y;
        float wi = zy * gp.x - zx * gp.y;
        float ch = fminf(sqrtf(wr * wr + wi * wi), 1.f);
        Se[g * ROWS + row] = r.x;
        Coh[g * ROWS + row] = ch;
        Ent[g * ROWS + row] = ent;
    }
}

// ---------------- K4: scalar decisions -------------------------------------
__global__ __launch_bounds__(256) void k_decide(
    const float* __restrict__ Se, const float* __restrict__ Coh, const float* __restrict__ Ent,
    int* __restrict__ frontier, int* __restrict__ mergeact, int* __restrict__ pruneF)
{
    __shared__ float cost[NNODES], ne[NNODES], cm[NNODES];
    int tid = threadIdx.x, wid = tid >> 6, lane = tid & 63;
    for (int gn = wid; gn < NNODES; gn += 4) {
        float a = 0.f, b = 0.f, cc = 0.f;
        for (int r = lane; r < ROWS; r += 64) {
            float ch = Coh[gn * ROWS + r];
            a += Ent[gn * ROWS + r] + 1.f - ch;
            b += Se[gn * ROWS + r];
            cc += ch;
        }
        #pragma unroll
        for (int m = 32; m >= 1; m >>= 1) {
            a += __shfl_xor(a, m); b += __shfl_xor(b, m); cc += __shfl_xor(cc, m);
        }
        if (lane == 0) { cost[gn] = a / (float)ROWS; ne[gn] = b; cm[gn] = cc / (float)ROWS; }
    }
    __syncthreads();
    if (tid == 0) {
        float mc[NNODES]; int sel[NNODES]; int act[NNODES];
        for (int gn = NNODES - 1; gn >= 0; --gn) {
            if (gn >= 15) { mc[gn] = cost[gn]; sel[gn] = 0; }
            else {
                float chc = mc[2 * gn + 1] + mc[2 * gn + 2];
                sel[gn] = (chc < cost[gn]) ? 1 : 0;
                mc[gn] = fminf(chc, cost[gn]);
            }
        }
        float total_e = ne[0];
        act[0] = 1;
        for (int gn = 1; gn < NNODES; ++gn) {
            int p = (gn - 1) >> 1;
            act[gn] = act[p] && sel[p];
        }
        for (int gn = 0; gn < NNODES; ++gn) {
            int isleaf = (gn >= 15);
            frontier[gn] = (act[gn] && (isleaf || !sel[gn])) ? 1 : 0;
            mergeact[gn] = (act[gn] && sel[gn] && !isleaf) ? 1 : 0;
            pruneF[gn] = ((ne[gn] / total_e < PRUNEF) || (cm[gn] < PRUNEF)) ? 1 : 0;
        }
    }
}

// ---------------- exact radix-select (rank-th smallest of n uint keys) -----
__device__ __forceinline__ uint radix_select_u(
    const uint* keys, int n, int rank, uint* hist, int tid)
{
    uint prefix = 0u, prefmask = 0u;
    int r = rank;
    for (int shift = 24; shift >= 0; shift -= 8) {
        hist[tid] = 0u;
        __syncthreads();
        for (int i = tid; i < n; i += 256) {
            uint k = keys[i];
            if ((k & prefmask) == prefix)
                atomicAdd(&hist[(k >> shift) & 255u], 1u);
        }
        __syncthreads();
        if (tid < 64) {
            uint c0 = hist[4 * tid + 0], c1 = hist[4 * tid + 1];
            uint c2 = hist[4 * tid + 2], c3 = hist[4 * tid + 3];
            uint s = c0 + c1 + c2 + c3;
            uint sc = s;
            #pragma unroll
            for (int o = 1; o < 64; o <<= 1) {
                uint v = __shfl_up(sc, o);
                if (tid >= o) sc += v;
            }
            uint p0 = sc - s;
            uint p1 = p0 + c0, p2 = p1 + c1, p3 = p2 + c2;
            uint rr = (uint)r;
            if (rr >= p0 && rr < p1)        { hist[256] = 4 * tid + 0; hist[257] = p0; }
            else if (rr >= p1 && rr < p2)   { hist[256] = 4 * tid + 1; hist[257] = p1; }
            else if (rr >= p2 && rr < p3)   { hist[256] = 4 * tid + 2; hist[257] = p2; }
            else if (rr >= p3 && rr < p3 + c3) { hist[256] = 4 * tid + 3; hist[257] = p3; }
        }
        __syncthreads();
        uint bin = hist[256];
        r -= (int)hist[257];
        prefix |= bin << shift;
        prefmask |= (255u << shift);
        __syncthreads();
    }
    return prefix;
}

// ---------------- K5: frontier leaf filter (regs MLP + radix median) -------
template<int D>
__global__ __launch_bounds__(256, 2) void k_filter(
    const float2* __restrict__ lev,
    const float* __restrict__ Se, const float* __restrict__ Coh,
    const int* __restrict__ frontier, const int* __restrict__ pruneF,
    float2* __restrict__ outS,
    const float* __restrict__ Wp, const float* __restrict__ bp,
    const float* __restrict__ Wo, const float* __restrict__ bo,
    const float* lfg_p, const float* sig_p, const float* hfg_p, const float* cut_p)
{
    constexpr int NODES = 1 << D;
    constexpr int ND = NN >> D;
    constexpr int EPT = ND / 256;
    __shared__ uint sortb[ND];
    __shared__ uint hist[258];

    int tid = threadIdx.x;
    int node = blockIdx.x & (NODES - 1);
    int row = blockIdx.x >> D;
    int g = (NODES - 1) + node;
    if (!frontier[g]) return;

    float lfg = *lfg_p, sigma = *sig_p, hfg = *hfg_p, cutoff = *cut_p;
    float bcv = (D == 0) ? 0.f : ((float)node + 0.5f) / (float)NODES;
    float coh = Coh[g * ROWS + row];
    float se  = Se[g * ROWS + row];
    float nle = logf(fmaxf(se * (1.f / (float)ND), EPSF));
    float dn = (float)D / (float)NLEV;
    float lbb = 1.f + lfg * expf(-(bcv * bcv) / (sigma * sigma));
    float hbd = hfg + (1.f - hfg) / (1.f + expf(-(cutoff - bcv) / sigma));
    float gbase = lbb * hbd * (1.f + lfg * coh) * (hfg + (1.f - hfg) * coh);
    float invnm1 = 1.f / (float)(ND - 1);

    // weights + per-block constant part of hidden pre-activations, in regs
    float w0r[12], w1r[12], w6r[12], wo0r[12], wo1r[12], hb[12];
    #pragma unroll
    for (int j = 0; j < 12; ++j) {
        w0r[j] = Wp[j * 7 + 0];
        w1r[j] = Wp[j * 7 + 1];
        w6r[j] = Wp[j * 7 + 6];
        hb[j] = bp[j] + nle * Wp[j * 7 + 2] + dn * Wp[j * 7 + 3]
              + bcv * Wp[j * 7 + 4] + coh * Wp[j * 7 + 5];
        wo0r[j] = Wo[j]; wo1r[j] = Wo[12 + j];
    }
    float bo0 = bo[0], bo1 = bo[1];

    const float2* c = lev + ((size_t)row << LOGN) + (size_t)node * ND;
    float2 kf[EPT];

    #pragma unroll
    for (int t = 0; t < EPT; ++t) {
        int i = tid + (t << 8);
        float2 cv = c[i];
        float m2 = cv.x * cv.x + cv.y * cv.y;
        float f0 = 0.5f * __logf(fmaxf(m2, 1e-12f));        // log(max(|c|,eps))
        float f1 = fast_atan2f(cv.y, cv.x) * INV_PIF;
        float f6 = (float)i * invnm1;
        float acc0 = bo0, acc1 = bo1;
        #pragma unroll
        for (int j = 0; j < 12; ++j) {
            float h = fmaf(f0, w0r[j], fmaf(f1, w1r[j], fmaf(f6, w6r[j], hb[j])));
            float s = h * fast_rcp(1.f + __expf(-h));       // silu
            acc0 = fmaf(s, wo0r[j], acc0);
            acc1 = fmaf(s, wo1r[j], acc1);
        }
        float gm = gbase * __expf(0.25f * tanh_fast(acc0));
        float dp = HALF_PIF * tanh_fast(acc1);
        float sp = __sinf(dp), cp = __cosf(dp);
        float fr = gm * (cv.x * cp - cv.y * sp);
        float fi = gm * (cv.x * sp + cv.y * cp);
        kf[t] = make_float2(fr, fi);
        float fm = gm * sqrtf(m2);                          // |filtered|
        sortb[i] = __float_as_uint(fm);
    }
    __syncthreads();

    uint va = radix_select_u(sortb, ND, ND / 2 - 1, hist, tid);
    uint vb = radix_select_u(sortb, ND, ND / 2, hist, tid);
    float nf = 0.5f * (__uint_as_float(va) + __uint_as_float(vb));
    float thr = (1.f - hbd) * nf;
    float pf = pruneF[g] ? (hfg * hfg) : 1.f;

    float2* o = outS + ((size_t)row << LOGN) + (size_t)node * ND;
    #pragma unroll
    for (int t = 0; t < EPT; ++t) {
        int i = tid + (t << 8);
        float fr = kf[t].x, fi = kf[t].y;
        float fm = sqrtf(fr * fr + fi * fi);
        float den = fmaxf(fm - thr, 0.f);
        float s = den * fast_rcp(fmaxf(fm, EPSF)) * pf;
        o[i] = make_float2(fr * s, fi * s);
    }
}

// ---------------- K6: bottom-up Haar merge in place ------------------------
__global__ __launch_bounds__(256) void k_merge(
    float2* __restrict__ outS, int pdepth, const int* __restrict__ mergeact)
{
    int nodes = 1 << pdepth;
    int nd = NN >> pdepth;
    int node = blockIdx.x & (nodes - 1);
    int row = blockIdx.x >> pdepth;
    int g = (nodes - 1) + node;
    if (!mergeact[g]) return;

    __shared__ float2 sh[NN];
    int tid = threadIdx.x;
    float2* base = outS + ((size_t)row << LOGN) + (size_t)node * nd;
    for (int i = tid; i < nd; i += 256) sh[i] = base[i];
    __syncthreads();
    int nh = nd >> 1;
    for (int i = tid; i < nh; i += 256) {
        float2 lo = sh[i], hi = sh[nh + i];
        float2 ev, od;
        ev.x = (lo.x + hi.x) * SQRT1_2F; ev.y = (lo.y + hi.y) * SQRT1_2F;
        od.x = (lo.x - hi.x) * SQRT1_2F; od.y = (lo.y - hi.y) * SQRT1_2F;
        base[2 * i]     = ev;
        base[2 * i + 1] = od;
    }
}

// ---------------- K7: IFFT + real part -------------------------------------
__global__ __launch_bounds__(256) void k_ifft(
    const float2* __restrict__ outS, float* __restrict__ out)
{
    __shared__ float2 sh[NN];
    int row = blockIdx.x, tid = threadIdx.x;
    const float2* sr = outS + ((size_t)row << LOGN);
    #pragma unroll
    for (int t = 0; t < NN / 256; ++t) {
        int i = tid + (t << 8);
        int r = __brev((uint)i) >> (32 - LOGN);
        sh[r] = sr[i];
    }
    __syncthreads();
    fft_lds(sh, tid, +1.f);
    float* orow = out + ((size_t)row << LOGN);
    #pragma unroll
    for (int t = 0; t < NN / 256; ++t) {
        int k = tid + (t << 8);
        orow[k] = sh[k].x * (1.0f / (float)NN);
    }
}

// ---------------- host launch ----------------------------------------------
extern "C" void kernel_launch(void* const* d_in, const int* in_sizes, int n_in,
                              void* d_out, int out_size, void* d_ws, size_t ws_size,
                              hipStream_t stream) {
    const float* x   = (const float*)d_in[0];
    const float* Wp  = (const float*)d_in[1];
    const float* bp  = (const float*)d_in[2];
    const float* Wo  = (const float*)d_in[3];
    const float* bo  = (const float*)d_in[4];
    const float* lfg = (const float*)d_in[5];
    const float* sig = (const float*)d_in[6];
    const float* hfg = (const float*)d_in[7];
    const float* cut = (const float*)d_in[8];
    float* out = (float*)d_out;

    size_t S = (size_t)ROWS * NN * sizeof(float2);   // 33,554,432 B
    size_t statsz = (size_t)3 * NNODES * ROWS * sizeof(float)
                  + (size_t)ROWS * sizeof(float2) + (size_t)3 * NNODES * sizeof(int);
    char* ws = (char*)d_ws;
    bool full = ws_size >= 6 * S + statsz;

    float2 *L0, *L1, *L2, *L3, *L4, *outS;
    char* statbase;
    if (full) {
        L0 = (float2*)(ws);
        L1 = (float2*)(ws + 1 * S);
        L2 = (float2*)(ws + 2 * S);
        L3 = (float2*)(ws + 3 * S);
        L4 = (float2*)(ws + 4 * S);
        outS = (float2*)(ws + 5 * S);
        statbase = ws + 6 * S;
    } else {
        if (ws_size < 3 * S + statsz) return;
        L0 = (float2*)(ws);          // levA
        L1 = (float2*)(ws + S);      // levB
        L2 = L3 = L4 = nullptr;
        outS = (float2*)(ws + 2 * S);
        statbase = ws + 3 * S;
    }
    float*  Se   = (float*)statbase;
    float*  Coh  = Se  + (size_t)NNODES * ROWS;
    float*  Ent  = Coh + (size_t)NNODES * ROWS;
    float2* gpuv = (float2*)(Ent + (size_t)NNODES * ROWS);
    int* frontier = (int*)(gpuv + ROWS);
    int* mergeact = frontier + NNODES;
    int* pruneF   = mergeact + NNODES;

    dim3 b(256);
    int hg = (ROWS * NN / 2) / 256;   // 8192 blocks for haar

    if (full) {
        // ---- single pyramid: levels persist ----
        k_fft_filter<<<dim3(ROWS), b, 0, stream>>>(x, L0, gpuv, lfg, sig, hfg, cut);
        k_stats<<<dim3(ROWS << 0), b, 0, stream>>>(L0, 0, gpuv, Se, Coh, Ent);
        k_haar<<<dim3(hg), b, 0, stream>>>(L0, L1, NN,      LOGN - 1);
        k_stats<<<dim3(ROWS << 1), b, 0, stream>>>(L1, 1, gpuv, Se, Coh, Ent);
        k_haar<<<dim3(hg), b, 0, stream>>>(L1, L2, NN >> 1, LOGN - 2);
        k_stats<<<dim3(ROWS << 2), b, 0, stream>>>(L2, 2, gpuv, Se, Coh, Ent);
        k_haar<<<dim3(hg), b, 0, stream>>>(L2, L3, NN >> 2, LOGN - 3);
        k_stats<<<dim3(ROWS << 3), b, 0, stream>>>(L3, 3, gpuv, Se, Coh, Ent);
        k_haar<<<dim3(hg), b, 0, stream>>>(L3, L4, NN >> 3, LOGN - 4);
        k_stats<<<dim3(ROWS << 4), b, 0, stream>>>(L4, 4, gpuv, Se, Coh, Ent);
        k_decide<<<dim3(1), b, 0, stream>>>(Se, Coh, Ent, frontier, mergeact, pruneF);

        k_filter<0><<<dim3(ROWS << 0), b, 0, stream>>>(L0, Se, Coh, frontier, pruneF, outS, Wp, bp, Wo, bo, lfg, sig, hfg, cut);
        k_filter<1><<<dim3(ROWS << 1), b, 0, stream>>>(L1, Se, Coh, frontier, pruneF, outS, Wp, bp, Wo, bo, lfg, sig, hfg, cut);
        k_filter<2><<<dim3(ROWS << 2), b, 0, stream>>>(L2, Se, Coh, frontier, pruneF, outS, Wp, bp, Wo, bo, lfg, sig, hfg, cut);
        k_filter<3><<<dim3(ROWS << 3), b, 0, stream>>>(L3, Se, Coh, frontier, pruneF, outS, Wp, bp, Wo, bo, lfg, sig, hfg, cut);
        k_filter<4><<<dim3(ROWS << 4), b, 0, stream>>>(L4, Se, Coh, frontier, pruneF, outS, Wp, bp, Wo, bo, lfg, sig, hfg, cut);
    } else {
        // ---- fallback: ping-pong, recompute pyramid for phase 2 ----
        float2* A = L0; float2* B = L1;
        k_fft_filter<<<dim3(ROWS), b, 0, stream>>>(x, A, gpuv, lfg, sig, hfg, cut);
        k_stats<<<dim3(ROWS << 0), b, 0, stream>>>(A, 0, gpuv, Se, Coh, Ent);
        k_haar<<<dim3(hg), b, 0, stream>>>(A, B, NN,      LOGN - 1);
        k_stats<<<dim3(ROWS << 1), b, 0, stream>>>(B, 1, gpuv, Se, Coh, Ent);
        k_haar<<<dim3(hg), b, 0, stream>>>(B, A, NN >> 1, LOGN - 2);
        k_stats<<<dim3(ROWS << 2), b, 0, stream>>>(A, 2, gpuv, Se, Coh, Ent);
        k_haar<<<dim3(hg), b, 0, stream>>>(A, B, NN >> 2, LOGN - 3);
        k_stats<<<dim3(ROWS << 3), b, 0, stream>>>(B, 3, gpuv, Se, Coh, Ent);
        k_haar<<<dim3(hg), b, 0, stream>>>(B, A, NN >> 3, LOGN - 4);
        k_stats<<<dim3(ROWS << 4), b, 0, stream>>>(A, 4, gpuv, Se, Coh, Ent);
        k_decide<<<dim3(1), b, 0, stream>>>(Se, Coh, Ent, frontier, mergeact, pruneF);

        k_fft_filter<<<dim3(ROWS), b, 0, stream>>>(x, A, gpuv, lfg, sig, hfg, cut);
        k_filter<0><<<dim3(ROWS << 0), b, 0, stream>>>(A, Se, Coh, frontier, pruneF, outS, Wp, bp, Wo, bo, lfg, sig, hfg, cut);
        k_haar<<<dim3(hg), b, 0, stream>>>(A, B, NN,      LOGN - 1);
        k_filter<1><<<dim3(ROWS << 1), b, 0, stream>>>(B, Se, Coh, frontier, pruneF, outS, Wp, bp, Wo, bo, lfg, sig, hfg, cut);
        k_haar<<<dim3(hg), b, 0, stream>>>(B, A, NN >> 1, LOGN - 2);
        k_filter<2><<<dim3(ROWS << 2), b, 0, stream>>>(A, Se, Coh, frontier, pruneF, outS, Wp, bp, Wo, bo, lfg, sig, hfg, cut);
        k_haar<<<dim3(hg), b, 0, stream>>>(A, B, NN >> 2, LOGN - 3);
        k_filter<3><<<dim3(ROWS << 3), b, 0, stream>>>(B, Se, Coh, frontier, pruneF, outS, Wp, bp, Wo, bo, lfg, sig, hfg, cut);
        k_haar<<<dim3(hg), b, 0, stream>>>(B, A, NN >> 3, LOGN - 4);
        k_filter<4><<<dim3(ROWS << 4), b, 0, stream>>>(A, Se, Coh, frontier, pruneF, outS, Wp, bp, Wo, bo, lfg, sig, hfg, cut);
    }

    k_merge<<<dim3(ROWS << 3), b, 0, stream>>>(outS, 3, mergeact);
    k_merge<<<dim3(ROWS << 2), b, 0, stream>>>(outS, 2, mergeact);
    k_merge<<<dim3(ROWS << 1), b, 0, stream>>>(outS, 1, mergeact);
    k_merge<<<dim3(ROWS << 0), b, 0, stream>>>(outS, 0, mergeact);

    k_ifft<<<dim3(ROWS), b, 0, stream>>>(outS, out);
}

// Round 3
// 193.327 us; speedup vs baseline: 5.0595x; 1.4663x over previous
//
#include <hip/hip_runtime.h>
#include <math.h>

#define NN      8192
#define LOGN    13
#define ROWS    512
#define NLEV    4
#define NNODES  31
#define EPSF    1e-6f
#define PRUNEF  0.05f
#define SQRT1_2F 0.70710678118654752f
#define TWO_PIF  6.28318530717958647692f
#define INV_PIF  0.31830988618379067f
#define HALF_PIF 1.57079632679489662f

typedef unsigned int uint;

// ---------------- fast math helpers ----------------
__device__ __forceinline__ float fast_rcp(float x)  { return __builtin_amdgcn_rcpf(x); }
__device__ __forceinline__ float fast_rsq(float x)  { return __builtin_amdgcn_rsqf(x); }

__device__ __forceinline__ float tanh_fast(float x) {
    float e = __expf(2.f * x);
    return 1.f - 2.f * fast_rcp(e + 1.f);
}

// atan2 via poly, ~1e-6 abs accuracy
__device__ __forceinline__ float fast_atan2f(float y, float x) {
    float ay = fabsf(y), ax = fabsf(x);
    float mx = fmaxf(ax, ay), mn = fminf(ax, ay);
    float a = (mx > 0.f) ? (mn * fast_rcp(mx)) : 0.f;
    bool big = a > 0.4142135679f;
    float t = big ? ((a - 1.f) * fast_rcp(a + 1.f)) : a;
    float z2 = t * t;
    float p = fmaf(8.05374449538e-2f, z2, -1.38776856032e-1f);
    p = fmaf(p, z2, 1.99777106478e-1f);
    p = fmaf(p, z2, -3.33329491539e-1f);
    float r = fmaf(p * z2, t, t);
    if (big) r += 0.78539816339744831f;
    if (ay > ax) r = 1.57079632679489662f - r;
    if (x < 0.f) r = 3.14159265358979323f - r;
    return copysignf(r, y);
}

// ---------------- in-LDS radix-2 FFT (N=8192, 256 threads) ----------------
__device__ __forceinline__ void fft_lds(float2* sh, int tid, float sgn) {
    for (int s = 1; s <= LOGN; ++s) {
        int half = 1 << (s - 1);
        float invm = 1.0f / (float)(1 << s);
        #pragma unroll
        for (int t = 0; t < (NN / 2) / 256; ++t) {
            int bf = tid + (t << 8);
            int j = bf & (half - 1);
            int pos = ((bf >> (s - 1)) << s) + j;
            float ang = sgn * TWO_PIF * (float)j * invm;
            float sw = __sinf(ang);
            float cw = __cosf(ang);
            float2 a = sh[pos];
            float2 b = sh[pos + half];
            float tr = cw * b.x - sw * b.y;
            float ti = cw * b.y + sw * b.x;
            sh[pos]        = make_float2(a.x + tr, a.y + ti);
            sh[pos + half] = make_float2(a.x - tr, a.y - ti);
        }
        __syncthreads();
    }
}

__device__ __forceinline__ void wave_red8(float* a) {
    #pragma unroll
    for (int m = 32; m >= 1; m >>= 1) {
        #pragma unroll
        for (int q = 0; q < 8; ++q) a[q] += __shfl_xor(a[q], m);
    }
}

// ---------------- K1: FFT + filter + full stats pyramid --------------------
__global__ __launch_bounds__(256, 2) void k_pre(
    const float* __restrict__ x, float2* __restrict__ L0,
    float* __restrict__ Se, float* __restrict__ Coh, float* __restrict__ Ent,
    const float* lfg_p, const float* sig_p, const float* hfg_p, const float* cut_p)
{
    __shared__ float2 sh[NN];        // 64KB
    __shared__ float4 red[256];      // 4KB
    __shared__ float nacc[16][4];
    __shared__ float2 gpsh;
    int row = blockIdx.x, tid = threadIdx.x;

    const float* xr = x + ((size_t)row << LOGN);
    #pragma unroll
    for (int t = 0; t < 32; ++t) {
        int i = tid + (t << 8);
        sh[__brev((uint)i) >> (32 - LOGN)] = make_float2(xr[i], 0.f);
    }
    __syncthreads();
    fft_lds(sh, tid, -1.f);

    float lfg = *lfg_p, sigma = *sig_p, hfg = *hfg_p, cutoff = *cut_p;
    float inv_gs = 1.f / fmaxf(sigma, 0.05f);
    float is2 = 1.f / (sigma * sigma);
    float se = 0.f, slg = 0.f, sux = 0.f, suy = 0.f;
    float2* o = L0 + ((size_t)row << LOGN);
    #pragma unroll
    for (int t = 0; t < 32; ++t) {
        int k = tid + (t << 8);
        float fk = (k < NN / 2) ? (float)k : (float)(k - NN);
        float f = fk * (1.0f / (float)NN);
        float r2 = f * f;
        float lfb = 1.f + lfg * __expf(-r2 * is2);
        float radius = sqrtf(r2 + 1e-12f);
        float gate = fast_rcp(1.f + __expf(-(cutoff - radius) * inv_gs));
        float mult = lfb * (hfg + (1.f - hfg) * gate);
        float2 c = sh[k];
        c.x *= mult; c.y *= mult;
        sh[k] = c;
        o[k] = c;
        float e = c.x * c.x + c.y * c.y;
        se += e;
        slg += e * __logf(fmaxf(e, 1e-30f));
        float inv = fminf(fast_rsq(e), 1e6f);
        sux += c.x * inv; suy += c.y * inv;
    }
    red[tid] = make_float4(se, slg, sux, suy);
    __syncthreads();
    for (int s = 128; s > 0; s >>= 1) {
        if (tid < s) {
            red[tid].x += red[tid + s].x; red[tid].y += red[tid + s].y;
            red[tid].z += red[tid + s].z; red[tid].w += red[tid + s].w;
        }
        __syncthreads();
    }
    if (tid == 0) {
        float4 r = red[0];
        float gx = r.z / (float)NN, gy = r.w / (float)NN;
        float ga = sqrtf(gx * gx + gy * gy);
        float im = 1.f / fmaxf(ga, EPSF);
        gpsh = make_float2(gx * im, gy * im);
        float denom = fmaxf(r.x, EPSF);
        Se[row]  = r.x;
        Ent[row] = __logf(denom) - r.y / denom;
        Coh[row] = fminf(ga * ga * im, 1.f);
    }
    __syncthreads();
    float2 gp = gpsh;

    // pyramid: split depth dp -> dp+1 in LDS, fused child stats
    for (int dp = 0; dp < 4; ++dp) {
        int lognd = LOGN - dp;           // parent seg log2
        int lognh = lognd - 1;
        int cpp = 1 << (4 - dp);         // chunks (of 256 pairs) per parent
        if (tid < 64) ((float*)nacc)[tid] = 0.f;
        __syncthreads();

        float4 pv[16];
        #pragma unroll
        for (int t = 0; t < 16; ++t) {
            int j = tid + (t << 8);
            int n = j >> lognh;
            int i = j & ((1 << lognh) - 1);
            pv[t] = *reinterpret_cast<const float4*>(&sh[(n << lognd) + 2 * i]);
        }
        __syncthreads();

        float acc[8] = {0,0,0,0,0,0,0,0};
        #pragma unroll
        for (int t = 0; t < 16; ++t) {
            int j = tid + (t << 8);
            int n = j >> lognh;
            int i = j & ((1 << lognh) - 1);
            float lox = (pv[t].x + pv[t].z) * SQRT1_2F;
            float loy = (pv[t].y + pv[t].w) * SQRT1_2F;
            float hix = (pv[t].x - pv[t].z) * SQRT1_2F;
            float hiy = (pv[t].y - pv[t].w) * SQRT1_2F;
            sh[(n << lognd) + i]                 = make_float2(lox, loy);
            sh[(n << lognd) + (1 << lognh) + i]  = make_float2(hix, hiy);
            float e1 = lox * lox + loy * loy;
            acc[0] += e1; acc[1] += e1 * __logf(fmaxf(e1, 1e-30f));
            float i1 = fminf(fast_rsq(e1), 1e6f);
            acc[2] += lox * i1; acc[3] += loy * i1;
            float e2 = hix * hix + hiy * hiy;
            acc[4] += e2; acc[5] += e2 * __logf(fmaxf(e2, 1e-30f));
            float i2 = fminf(fast_rsq(e2), 1e6f);
            acc[6] += hix * i2; acc[7] += hiy * i2;
            if (((t + 1) & (cpp - 1)) == 0) {
                wave_red8(acc);
                if ((tid & 63) == 0) {
                    atomicAdd(&nacc[2 * n][0], acc[0]); atomicAdd(&nacc[2 * n][1], acc[1]);
                    atomicAdd(&nacc[2 * n][2], acc[2]); atomicAdd(&nacc[2 * n][3], acc[3]);
                    atomicAdd(&nacc[2 * n + 1][0], acc[4]); atomicAdd(&nacc[2 * n + 1][1], acc[5]);
                    atomicAdd(&nacc[2 * n + 1][2], acc[6]); atomicAdd(&nacc[2 * n + 1][3], acc[7]);
                }
                #pragma unroll
                for (int q = 0; q < 8; ++q) acc[q] = 0.f;
            }
        }
        __syncthreads();
        int cn = 2 << dp;                    // children count
        if (tid < cn) {
            float E = nacc[tid][0], SL = nacc[tid][1], ZX = nacc[tid][2], ZY = nacc[tid][3];
            int ndc = 1 << lognh;
            float denom = fmaxf(E, EPSF);
            float ent = __logf(denom) - SL / denom;
            float zx = ZX / (float)ndc, zy = ZY / (float)ndc;
            float wr = zx * gp.x + zy * gp.y;
            float wi = zy * gp.x - zx * gp.y;
            float ch = fminf(sqrtf(wr * wr + wi * wi), 1.f);
            int g = (cn - 1) + tid;
            Se[g * ROWS + row] = E; Coh[g * ROWS + row] = ch; Ent[g * ROWS + row] = ent;
        }
        __syncthreads();
    }
}

// ---------------- K2: scalar decisions -------------------------------------
__global__ __launch_bounds__(256) void k_decide(
    const float* __restrict__ Se, const float* __restrict__ Coh, const float* __restrict__ Ent,
    int* __restrict__ frontier, int* __restrict__ mergeact, int* __restrict__ pruneF)
{
    __shared__ float cost[NNODES], ne[NNODES], cm[NNODES];
    int tid = threadIdx.x, wid = tid >> 6, lane = tid & 63;
    for (int gn = wid; gn < NNODES; gn += 4) {
        float a = 0.f, b = 0.f, cc = 0.f;
        for (int r = lane; r < ROWS; r += 64) {
            float ch = Coh[gn * ROWS + r];
            a += Ent[gn * ROWS + r] + 1.f - ch;
            b += Se[gn * ROWS + r];
            cc += ch;
        }
        #pragma unroll
        for (int m = 32; m >= 1; m >>= 1) {
            a += __shfl_xor(a, m); b += __shfl_xor(b, m); cc += __shfl_xor(cc, m);
        }
        if (lane == 0) { cost[gn] = a / (float)ROWS; ne[gn] = b; cm[gn] = cc / (float)ROWS; }
    }
    __syncthreads();
    if (tid == 0) {
        float mc[NNODES]; int sel[NNODES]; int act[NNODES];
        for (int gn = NNODES - 1; gn >= 0; --gn) {
            if (gn >= 15) { mc[gn] = cost[gn]; sel[gn] = 0; }
            else {
                float chc = mc[2 * gn + 1] + mc[2 * gn + 2];
                sel[gn] = (chc < cost[gn]) ? 1 : 0;
                mc[gn] = fminf(chc, cost[gn]);
            }
        }
        float total_e = ne[0];
        act[0] = 1;
        for (int gn = 1; gn < NNODES; ++gn) {
            int p = (gn - 1) >> 1;
            act[gn] = act[p] && sel[p];
        }
        for (int gn = 0; gn < NNODES; ++gn) {
            int isleaf = (gn >= 15);
            frontier[gn] = (act[gn] && (isleaf || !sel[gn])) ? 1 : 0;
            mergeact[gn] = (act[gn] && sel[gn] && !isleaf) ? 1 : 0;
            pruneF[gn] = ((ne[gn] / total_e < PRUNEF) || (cm[gn] < PRUNEF)) ? 1 : 0;
        }
    }
}

// ---------------- histogram select helpers ---------------------------------
template<int NBINS, int BSHIFT, int PSHIFT>
__device__ __forceinline__ void hist_build(
    const float2* sh, int eb, int cpn, int tid, uint* hist, uint pval)
{
    for (int k = tid; k < NBINS; k += 256) hist[k] = 0u;
    __syncthreads();
    for (int c = 0; c < cpn; ++c) {
        int p = eb + tid + (c << 8);
        float2 v = sh[p];
        float fm = sqrtf(v.x * v.x + v.y * v.y);
        uint u = __float_as_uint(fm);
        bool ok = true;
        if (PSHIFT < 32) ok = ((u >> PSHIFT) == pval);
        if (ok) atomicAdd(&hist[(u >> BSHIFT) & (NBINS - 1)], 1u);
    }
    __syncthreads();
}

template<int NBINS>
__device__ __forceinline__ uint2 hist_locate(
    const uint* hist, int tid, uint r, uint* wsum, uint* selres)
{
    constexpr int PER = NBINS / 256;
    uint loc[PER]; uint s = 0;
    #pragma unroll
    for (int k = 0; k < PER; ++k) { loc[k] = hist[tid * PER + k]; s += loc[k]; }
    uint sc = s;
    #pragma unroll
    for (int o = 1; o < 64; o <<= 1) {
        uint v = __shfl_up(sc, o);
        if ((tid & 63) >= o) sc += v;
    }
    if ((tid & 63) == 63) wsum[tid >> 6] = sc;
    __syncthreads();
    uint wb = 0;
    #pragma unroll
    for (int w = 0; w < 4; ++w) if (w < (tid >> 6)) wb += wsum[w];
    uint c0 = wb + sc - s;
    #pragma unroll
    for (int k = 0; k < PER; ++k) {
        if (r >= c0 && r < c0 + loc[k]) { selres[0] = (uint)(tid * PER + k); selres[1] = c0; }
        c0 += loc[k];
    }
    __syncthreads();
    uint2 res = make_uint2(selres[0], selres[1]);
    __syncthreads();
    return res;
}

// full 3-pass exact select of rank r (31-bit non-negative float keys)
__device__ __forceinline__ uint select_rank(
    const float2* sh, int eb, int cpn, int tid, uint* hist, uint* wsum, uint* selres,
    uint r, uint b1, uint base1)
{
    uint rr = r - base1;
    hist_build<2048, 9, 20>(sh, eb, cpn, tid, hist, b1);
    uint2 B = hist_locate<2048>(hist, tid, rr, wsum, selres);
    rr -= B.y;
    hist_build<512, 0, 9>(sh, eb, cpn, tid, hist, (b1 << 11) | B.x);
    uint2 C = hist_locate<512>(hist, tid, rr, wsum, selres);
    return (b1 << 20) | (B.x << 9) | C.x;
}

// ---------------- K3: apply (pyramid walk + filter + merge + ifft) ---------
__global__ __launch_bounds__(256, 2) void k_apply(
    const float2* __restrict__ L0,
    const float* __restrict__ Se, const float* __restrict__ Coh,
    const int* __restrict__ frontier, const int* __restrict__ mergeact,
    const int* __restrict__ pruneF,
    float* __restrict__ out,
    const float* __restrict__ Wp, const float* __restrict__ bp,
    const float* __restrict__ Wo, const float* __restrict__ bo,
    const float* lfg_p, const float* sig_p, const float* hfg_p, const float* cut_p)
{
    __shared__ float2 sh[NN];        // 64KB
    __shared__ uint hist[2048];      // 8KB
    __shared__ uint wsum[4];
    __shared__ uint selres[2];
    __shared__ float wsh[122];
    __shared__ int fF[NNODES], fM[NNODES], fP[NNODES];

    int row = blockIdx.x, tid = threadIdx.x;
    if (tid < NNODES) { fF[tid] = frontier[tid]; fM[tid] = mergeact[tid]; fP[tid] = pruneF[tid]; }
    if (tid < 84) wsh[tid] = Wp[tid];
    else if (tid < 96) wsh[tid] = bp[tid - 84];
    else if (tid < 120) wsh[tid] = Wo[tid - 96];
    else if (tid < 122) wsh[tid] = bo[tid - 120];

    const float2* src = L0 + ((size_t)row << LOGN);
    #pragma unroll
    for (int t = 0; t < 32; ++t) { int k = tid + (t << 8); sh[k] = src[k]; }
    __syncthreads();

    float lfg = *lfg_p, sigma = *sig_p, hfg = *hfg_p, cutoff = *cut_p;
    // hot-loop weights in regs
    float w0r[12], w1r[12], w6r[12], wo0r[12], wo1r[12];
    #pragma unroll
    for (int j = 0; j < 12; ++j) {
        w0r[j] = wsh[j * 7 + 0]; w1r[j] = wsh[j * 7 + 1]; w6r[j] = wsh[j * 7 + 6];
        wo0r[j] = wsh[96 + j]; wo1r[j] = wsh[108 + j];
    }
    float bo0 = wsh[120], bo1 = wsh[121];

    // ---- walk down ----
    for (int d = 0; d <= 4; ++d) {
        int nodes = 1 << d;
        int lognd = LOGN - d;
        int nd = 1 << lognd;
        int bg = nodes - 1;
        int cpn = 1 << (lognd - 8);
        for (int n = 0; n < nodes; ++n) {
            if (!fF[bg + n]) continue;
            int g = bg + n;
            int eb = n << lognd;
            float bcv = (d == 0) ? 0.f : ((float)n + 0.5f) / (float)nodes;
            float coh = Coh[g * ROWS + row];
            float sev = Se[g * ROWS + row];
            float nle = __logf(fmaxf(sev / (float)nd, EPSF));
            float dnv = (float)d * 0.25f;
            float lbb = 1.f + lfg * __expf(-(bcv * bcv) / (sigma * sigma));
            float hbd = hfg + (1.f - hfg) * fast_rcp(1.f + __expf(-(cutoff - bcv) / sigma));
            float gbase = lbb * hbd * (1.f + lfg * coh) * (hfg + (1.f - hfg) * coh);
            float invnm1 = 1.f / (float)(nd - 1);
            float hb[12];
            #pragma unroll
            for (int j = 0; j < 12; ++j)
                hb[j] = wsh[84 + j] + nle * wsh[j * 7 + 2] + dnv * wsh[j * 7 + 3]
                      + bcv * wsh[j * 7 + 4] + coh * wsh[j * 7 + 5];

            // MLP filter in place
            for (int c = 0; c < cpn; ++c) {
                int i = tid + (c << 8);
                int p = eb + i;
                float2 cv = sh[p];
                float m2 = cv.x * cv.x + cv.y * cv.y;
                float f0 = 0.5f * __logf(fmaxf(m2, 1e-12f));
                float f1 = fast_atan2f(cv.y, cv.x) * INV_PIF;
                float f6 = (float)i * invnm1;
                float acc0 = bo0, acc1 = bo1;
                #pragma unroll
                for (int j = 0; j < 12; ++j) {
                    float h = fmaf(f0, w0r[j], fmaf(f1, w1r[j], fmaf(f6, w6r[j], hb[j])));
                    float s = h * fast_rcp(1.f + __expf(-h));
                    acc0 = fmaf(s, wo0r[j], acc0);
                    acc1 = fmaf(s, wo1r[j], acc1);
                }
                float gm = gbase * __expf(0.25f * tanh_fast(acc0));
                float dph = HALF_PIF * tanh_fast(acc1);
                float sp = __sinf(dph), cp = __cosf(dph);
                float fr = gm * (cv.x * cp - cv.y * sp);
                float fi = gm * (cv.x * sp + cv.y * cp);
                sh[p] = make_float2(fr, fi);
            }
            __syncthreads();

            // exact median of |filtered| (two middle ranks)
            uint r1 = (uint)(nd / 2 - 1), r2 = (uint)(nd / 2);
            hist_build<2048, 20, 32>(sh, eb, cpn, tid, hist, 0u);
            uint2 A1 = hist_locate<2048>(hist, tid, r1, wsum, selres);
            uint2 A2 = hist_locate<2048>(hist, tid, r2, wsum, selres);
            uint va = select_rank(sh, eb, cpn, tid, hist, wsum, selres, r1, A1.x, A1.y);
            uint vb = select_rank(sh, eb, cpn, tid, hist, wsum, selres, r2, A2.x, A2.y);
            float nf = 0.5f * (__uint_as_float(va) + __uint_as_float(vb));
            float thr = (1.f - hbd) * nf;
            float pf = fP[g] ? (hfg * hfg) : 1.f;

            for (int c = 0; c < cpn; ++c) {
                int p = eb + tid + (c << 8);
                float2 v = sh[p];
                float fm = sqrtf(v.x * v.x + v.y * v.y);
                float den = fmaxf(fm - thr, 0.f);
                float s = den * fast_rcp(fmaxf(fm, EPSF)) * pf;
                sh[p] = make_float2(v.x * s, v.y * s);
            }
            __syncthreads();
        }

        bool anyM = false;
        for (int n = 0; n < nodes; ++n) anyM |= (fM[bg + n] != 0);
        if (!anyM || d == 4) break;

        // split mergeact nodes: parents at depth d, in place
        int lognh = lognd - 1;
        float4 pv[16];
        #pragma unroll
        for (int t = 0; t < 16; ++t) {
            int j = tid + (t << 8);
            int n = j >> lognh;
            if (fM[bg + n])
                pv[t] = *reinterpret_cast<const float4*>(&sh[(n << lognd) + 2 * (j & ((1 << lognh) - 1))]);
        }
        __syncthreads();
        #pragma unroll
        for (int t = 0; t < 16; ++t) {
            int j = tid + (t << 8);
            int n = j >> lognh;
            if (fM[bg + n]) {
                int i = j & ((1 << lognh) - 1);
                float2 lo, hi;
                lo.x = (pv[t].x + pv[t].z) * SQRT1_2F; lo.y = (pv[t].y + pv[t].w) * SQRT1_2F;
                hi.x = (pv[t].x - pv[t].z) * SQRT1_2F; hi.y = (pv[t].y - pv[t].w) * SQRT1_2F;
                sh[(n << lognd) + i] = lo;
                sh[(n << lognd) + (1 << lognh) + i] = hi;
            }
        }
        __syncthreads();
    }

    // ---- merge up ----
    for (int d = 3; d >= 0; --d) {
        int nodes = 1 << d;
        int bg = nodes - 1;
        bool anyM = false;
        for (int n = 0; n < nodes; ++n) anyM |= (fM[bg + n] != 0);
        if (!anyM) continue;
        int lognd = LOGN - d;
        int lognh = lognd - 1;
        float2 lo[16], hi[16];
        #pragma unroll
        for (int t = 0; t < 16; ++t) {
            int j = tid + (t << 8);
            int n = j >> lognh;
            if (fM[bg + n]) {
                int i = j & ((1 << lognh) - 1);
                lo[t] = sh[(n << lognd) + i];
                hi[t] = sh[(n << lognd) + (1 << lognh) + i];
            }
        }
        __syncthreads();
        #pragma unroll
        for (int t = 0; t < 16; ++t) {
            int j = tid + (t << 8);
            int n = j >> lognh;
            if (fM[bg + n]) {
                int i = j & ((1 << lognh) - 1);
                float4 w;
                w.x = (lo[t].x + hi[t].x) * SQRT1_2F; w.y = (lo[t].y + hi[t].y) * SQRT1_2F;
                w.z = (lo[t].x - hi[t].x) * SQRT1_2F; w.w = (lo[t].y - hi[t].y) * SQRT1_2F;
                *reinterpret_cast<float4*>(&sh[(n << lognd) + 2 * i]) = w;
            }
        }
        __syncthreads();
    }

    // ---- in-place bit-reverse + inverse FFT + real out ----
    #pragma unroll
    for (int t = 0; t < 32; ++t) {
        int p = tid + (t << 8);
        int r = __brev((uint)p) >> (32 - LOGN);
        if (p < r) { float2 a = sh[p], b2 = sh[r]; sh[p] = b2; sh[r] = a; }
    }
    __syncthreads();
    fft_lds(sh, tid, +1.f);
    float* orow = out + ((size_t)row << LOGN);
    #pragma unroll
    for (int t = 0; t < 32; ++t) {
        int k = tid + (t << 8);
        orow[k] = sh[k].x * (1.0f / (float)NN);
    }
}

// ---------------- host launch ----------------------------------------------
extern "C" void kernel_launch(void* const* d_in, const int* in_sizes, int n_in,
                              void* d_out, int out_size, void* d_ws, size_t ws_size,
                              hipStream_t stream) {
    const float* x   = (const float*)d_in[0];
    const float* Wp  = (const float*)d_in[1];
    const float* bp  = (const float*)d_in[2];
    const float* Wo  = (const float*)d_in[3];
    const float* bo  = (const float*)d_in[4];
    const float* lfg = (const float*)d_in[5];
    const float* sig = (const float*)d_in[6];
    const float* hfg = (const float*)d_in[7];
    const float* cut = (const float*)d_in[8];
    float* out = (float*)d_out;

    size_t S = (size_t)ROWS * NN * sizeof(float2);   // 33,554,432 B
    char* ws = (char*)d_ws;
    float2* L0 = (float2*)ws;
    float*  Se   = (float*)(ws + S);
    float*  Coh  = Se  + (size_t)NNODES * ROWS;
    float*  Ent  = Coh + (size_t)NNODES * ROWS;
    int* frontier = (int*)(Ent + (size_t)NNODES * ROWS);
    int* mergeact = frontier + NNODES;
    int* pruneF   = mergeact + NNODES;
    size_t need = (size_t)((char*)(pruneF + NNODES) - ws);
    if (ws_size < need) return;

    dim3 b(256);
    k_pre<<<dim3(ROWS), b, 0, stream>>>(x, L0, Se, Coh, Ent, lfg, sig, hfg, cut);
    k_decide<<<dim3(1), b, 0, stream>>>(Se, Coh, Ent, frontier, mergeact, pruneF);
    k_apply<<<dim3(ROWS), b, 0, stream>>>(L0, Se, Coh, frontier, mergeact, pruneF,
                                          out, Wp, bp, Wo, bo, lfg, sig, hfg, cut);
}

// Round 4
// 169.407 us; speedup vs baseline: 5.7739x; 1.1412x over previous
//
#include <hip/hip_runtime.h>
#include <math.h>

#define NN      8192
#define LOGN    13
#define ROWS    512
#define NT      512
#define NNODES  31
#define EPSF    1e-6f
#define PRUNEF  0.05f
#define SQRT1_2F 0.70710678118654752f
#define TWO_PIF  6.28318530717958647692f
#define INV_PIF  0.31830988618379067f
#define HALF_PIF 1.57079632679489662f

typedef unsigned int uint;

// ---------------- fast math helpers ----------------
__device__ __forceinline__ float fast_rcp(float x)  { return __builtin_amdgcn_rcpf(x); }
__device__ __forceinline__ float fast_rsq(float x)  { return __builtin_amdgcn_rsqf(x); }

__device__ __forceinline__ float tanh_fast(float x) {
    float e = __expf(2.f * x);
    return 1.f - 2.f * fast_rcp(e + 1.f);
}

__device__ __forceinline__ float fast_atan2f(float y, float x) {
    float ay = fabsf(y), ax = fabsf(x);
    float mx = fmaxf(ax, ay), mn = fminf(ax, ay);
    float a = (mx > 0.f) ? (mn * fast_rcp(mx)) : 0.f;
    bool big = a > 0.4142135679f;
    float t = big ? ((a - 1.f) * fast_rcp(a + 1.f)) : a;
    float z2 = t * t;
    float p = fmaf(8.05374449538e-2f, z2, -1.38776856032e-1f);
    p = fmaf(p, z2, 1.99777106478e-1f);
    p = fmaf(p, z2, -3.33329491539e-1f);
    float r = fmaf(p * z2, t, t);
    if (big) r += 0.78539816339744831f;
    if (ay > ax) r = 1.57079632679489662f - r;
    if (x < 0.f) r = 3.14159265358979323f - r;
    return copysignf(r, y);
}

// ---------------- in-LDS radix-2 FFT (N=8192, 512 threads) ----------------
__device__ __forceinline__ void fft_lds(float2* sh, int tid, float sgn) {
    for (int s = 1; s <= LOGN; ++s) {
        int half = 1 << (s - 1);
        float invm = 1.0f / (float)(1 << s);
        #pragma unroll
        for (int t = 0; t < 8; ++t) {
            int bf = tid + (t << 9);
            int j = bf & (half - 1);
            int pos = ((bf >> (s - 1)) << s) + j;
            float ang = sgn * TWO_PIF * (float)j * invm;
            float sw = __sinf(ang);
            float cw = __cosf(ang);
            float2 a = sh[pos];
            float2 b = sh[pos + half];
            float tr = cw * b.x - sw * b.y;
            float ti = cw * b.y + sw * b.x;
            sh[pos]        = make_float2(a.x + tr, a.y + ti);
            sh[pos + half] = make_float2(a.x - tr, a.y - ti);
        }
        __syncthreads();
    }
}

__device__ __forceinline__ void wave_red8(float* a) {
    #pragma unroll
    for (int m = 32; m >= 1; m >>= 1) {
        #pragma unroll
        for (int q = 0; q < 8; ++q) a[q] += __shfl_xor(a[q], m);
    }
}

// ---------------- K1: FFT + filter + stats pyramid + store LEAVES ----------
__global__ __launch_bounds__(NT, 4) void k_pre(
    const float* __restrict__ x, float2* __restrict__ Lv,
    float* __restrict__ Se, float* __restrict__ Coh, float* __restrict__ Ent,
    const float* lfg_p, const float* sig_p, const float* hfg_p, const float* cut_p)
{
    __shared__ float2 sh[NN];                 // 64KB
    __shared__ __align__(16) uint histred[2048];  // 8KB, used as float4 red[512]
    __shared__ float nacc[16][4];
    __shared__ float2 gpsh;
    int row = blockIdx.x, tid = threadIdx.x;
    float lfg = *lfg_p, sigma = *sig_p, hfg = *hfg_p, cutoff = *cut_p;
    float4* red = (float4*)histred;

    const float* xr = x + ((size_t)row << LOGN);
    #pragma unroll
    for (int t = 0; t < 16; ++t) {
        int i = tid + (t << 9);
        sh[__brev((uint)i) >> (32 - LOGN)] = make_float2(xr[i], 0.f);
    }
    __syncthreads();
    fft_lds(sh, tid, -1.f);

    float inv_gs = 1.f / fmaxf(sigma, 0.05f);
    float is2 = 1.f / (sigma * sigma);
    float se = 0.f, slg = 0.f, sux = 0.f, suy = 0.f;
    #pragma unroll
    for (int t = 0; t < 16; ++t) {
        int k = tid + (t << 9);
        float fk = (k < NN / 2) ? (float)k : (float)(k - NN);
        float f = fk * (1.0f / (float)NN);
        float r2 = f * f;
        float lfb = 1.f + lfg * __expf(-r2 * is2);
        float radius = sqrtf(r2 + 1e-12f);
        float gate = fast_rcp(1.f + __expf(-(cutoff - radius) * inv_gs));
        float mult = lfb * (hfg + (1.f - hfg) * gate);
        float2 c = sh[k];
        c.x *= mult; c.y *= mult;
        sh[k] = c;
        float e = c.x * c.x + c.y * c.y;
        se += e;
        slg += e * __logf(fmaxf(e, 1e-30f));
        float inv = fminf(fast_rsq(e), 1e6f);
        sux += c.x * inv; suy += c.y * inv;
    }
    red[tid] = make_float4(se, slg, sux, suy);
    __syncthreads();
    for (int s = NT / 2; s > 0; s >>= 1) {
        if (tid < s) {
            red[tid].x += red[tid + s].x; red[tid].y += red[tid + s].y;
            red[tid].z += red[tid + s].z; red[tid].w += red[tid + s].w;
        }
        __syncthreads();
    }
    if (tid == 0) {
        float4 r = red[0];
        float gx = r.z / (float)NN, gy = r.w / (float)NN;
        float ga = sqrtf(gx * gx + gy * gy);
        float im = 1.f / fmaxf(ga, EPSF);
        gpsh = make_float2(gx * im, gy * im);
        float denom = fmaxf(r.x, EPSF);
        Se[row]  = r.x;
        Ent[row] = __logf(denom) - r.y / denom;
        Coh[row] = fminf(ga * ga * im, 1.f);
    }
    __syncthreads();
    float2 gp = gpsh;

    // split pyramid with fused child stats (in place)
    for (int dp = 0; dp < 4; ++dp) {
        int lognd = LOGN - dp, lognh = lognd - 1;
        int cppm1 = (1 << (3 - dp)) - 1;          // chunks-per-parent - 1
        if (tid < 64) ((float*)nacc)[tid] = 0.f;
        __syncthreads();
        float4 pv[8];
        #pragma unroll
        for (int t = 0; t < 8; ++t) {
            int j = tid + (t << 9);
            int n = j >> lognh;
            int i = j & ((1 << lognh) - 1);
            pv[t] = *reinterpret_cast<const float4*>(&sh[(n << lognd) + 2 * i]);
        }
        __syncthreads();
        float acc[8] = {0,0,0,0,0,0,0,0};
        #pragma unroll
        for (int t = 0; t < 8; ++t) {
            int j = tid + (t << 9);
            int n = j >> lognh;
            int i = j & ((1 << lognh) - 1);
            float lox = (pv[t].x + pv[t].z) * SQRT1_2F;
            float loy = (pv[t].y + pv[t].w) * SQRT1_2F;
            float hix = (pv[t].x - pv[t].z) * SQRT1_2F;
            float hiy = (pv[t].y - pv[t].w) * SQRT1_2F;
            sh[(n << lognd) + i]                = make_float2(lox, loy);
            sh[(n << lognd) + (1 << lognh) + i] = make_float2(hix, hiy);
            float e1 = lox * lox + loy * loy;
            acc[0] += e1; acc[1] += e1 * __logf(fmaxf(e1, 1e-30f));
            float i1 = fminf(fast_rsq(e1), 1e6f);
            acc[2] += lox * i1; acc[3] += loy * i1;
            float e2 = hix * hix + hiy * hiy;
            acc[4] += e2; acc[5] += e2 * __logf(fmaxf(e2, 1e-30f));
            float i2 = fminf(fast_rsq(e2), 1e6f);
            acc[6] += hix * i2; acc[7] += hiy * i2;
            if (((t + 1) & cppm1) == 0) {
                wave_red8(acc);
                if ((tid & 63) == 0) {
                    atomicAdd(&nacc[2*n][0], acc[0]); atomicAdd(&nacc[2*n][1], acc[1]);
                    atomicAdd(&nacc[2*n][2], acc[2]); atomicAdd(&nacc[2*n][3], acc[3]);
                    atomicAdd(&nacc[2*n+1][0], acc[4]); atomicAdd(&nacc[2*n+1][1], acc[5]);
                    atomicAdd(&nacc[2*n+1][2], acc[6]); atomicAdd(&nacc[2*n+1][3], acc[7]);
                }
                #pragma unroll
                for (int q = 0; q < 8; ++q) acc[q] = 0.f;
            }
        }
        __syncthreads();
        int cn = 2 << dp;
        if (tid < cn) {
            float E = nacc[tid][0], SL = nacc[tid][1], ZX = nacc[tid][2], ZY = nacc[tid][3];
            float denom = fmaxf(E, EPSF);
            float ent = __logf(denom) - SL / denom;
            float invn = 1.f / (float)(1 << lognh);
            float zx = ZX * invn, zy = ZY * invn;
            float wr = zx * gp.x + zy * gp.y;
            float wi = zy * gp.x - zx * gp.y;
            float ch = fminf(sqrtf(wr * wr + wi * wi), 1.f);
            int g = cn - 1 + tid;
            Se[g * ROWS + row] = E; Coh[g * ROWS + row] = ch; Ent[g * ROWS + row] = ent;
        }
        __syncthreads();
    }

    // store depth-4 leaves
    float4* lrow = (float4*)(Lv + ((size_t)row << LOGN));
    const float4* s4 = (const float4*)sh;
    #pragma unroll
    for (int t = 0; t < 8; ++t) { int k = tid + (t << 9); lrow[k] = s4[k]; }
}

// ---------------- decide (run redundantly per block) -----------------------
__device__ __forceinline__ void dev_decide(
    const float* __restrict__ Se, const float* __restrict__ Coh, const float* __restrict__ Ent,
    int tid, int row_unused, float* dtmp, int* fF, int* fP)
{
    float* dcost = dtmp; float* dne = dtmp + NNODES; float* dcm = dtmp + 2 * NNODES;
    int wid = tid >> 6, lane = tid & 63;
    for (int gn = wid; gn < NNODES; gn += 8) {
        float a = 0.f, b = 0.f, cc = 0.f;
        #pragma unroll
        for (int rr = 0; rr < ROWS / 64; ++rr) {
            int r = lane + (rr << 6);
            float ch = Coh[gn * ROWS + r];
            a += Ent[gn * ROWS + r] + 1.f - ch;
            b += Se[gn * ROWS + r];
            cc += ch;
        }
        #pragma unroll
        for (int m = 32; m >= 1; m >>= 1) {
            a += __shfl_xor(a, m); b += __shfl_xor(b, m); cc += __shfl_xor(cc, m);
        }
        if (lane == 0) { dcost[gn] = a / (float)ROWS; dne[gn] = b; dcm[gn] = cc / (float)ROWS; }
    }
    __syncthreads();
    if (tid == 0) {
        float mc[NNODES]; int sel[NNODES]; int act[NNODES];
        for (int gn = NNODES - 1; gn >= 0; --gn) {
            if (gn >= 15) { mc[gn] = dcost[gn]; sel[gn] = 0; }
            else {
                float chc = mc[2 * gn + 1] + mc[2 * gn + 2];
                sel[gn] = (chc < dcost[gn]) ? 1 : 0;
                mc[gn] = fminf(chc, dcost[gn]);
            }
        }
        float total_e = dne[0];
        act[0] = 1;
        for (int gn = 1; gn < NNODES; ++gn) {
            int p = (gn - 1) >> 1;
            act[gn] = act[p] && sel[p];
        }
        for (int gn = 0; gn < NNODES; ++gn) {
            int isleaf = (gn >= 15);
            fF[gn] = (act[gn] && (isleaf || !sel[gn])) ? 1 : 0;
            fP[gn] = ((dne[gn] / total_e < PRUNEF) || (dcm[gn] < PRUNEF)) ? 1 : 0;
        }
    }
    __syncthreads();
}

// ---------------- histogram select helpers ---------------------------------
__device__ __forceinline__ uint key_at(const float2* sh, int p) {
    float2 v = sh[p];
    return __float_as_uint(sqrtf(v.x * v.x + v.y * v.y));
}

template<int NBINS>
__device__ __forceinline__ uint2 hist_locate(
    const uint* hist, int tid, uint r, uint* wsum, uint* selres)
{
    constexpr int PER = NBINS / NT;
    uint loc[PER]; uint s = 0;
    #pragma unroll
    for (int k = 0; k < PER; ++k) { loc[k] = hist[tid * PER + k]; s += loc[k]; }
    uint sc = s;
    #pragma unroll
    for (int o = 1; o < 64; o <<= 1) {
        uint v = __shfl_up(sc, o);
        if ((tid & 63) >= o) sc += v;
    }
    int wid = tid >> 6;
    if ((tid & 63) == 63) wsum[wid] = sc;
    __syncthreads();
    uint wb = 0;
    #pragma unroll
    for (int w = 0; w < 8; ++w) if (w < wid) wb += wsum[w];
    uint c0 = wb + sc - s;
    #pragma unroll
    for (int k = 0; k < PER; ++k) {
        if (r >= c0 && r < c0 + loc[k]) { selres[0] = (uint)(tid * PER + k); selres[1] = c0; }
        c0 += loc[k];
    }
    __syncthreads();
    uint2 res = make_uint2(selres[0], selres[1]);
    __syncthreads();
    return res;
}

// exact median: typically 3 data scans, worst 4
__device__ float median_node(
    const float2* sh, int eb, int ept, int nd, int tid,
    uint* hist, uint* wsum, uint* selres)
{
    uint r1 = (uint)(nd / 2 - 1), r2 = (uint)(nd / 2);
    // scan 1: coarse bins = bits 30..20
    for (int k = tid; k < 2048; k += NT) hist[k] = 0u;
    __syncthreads();
    for (int c = 0; c < ept; ++c) {
        uint k = key_at(sh, eb + tid + (c << 9));
        atomicAdd(&hist[k >> 20], 1u);
    }
    __syncthreads();
    uint2 A1 = hist_locate<2048>(hist, tid, r1, wsum, selres);
    uint2 A2 = hist_locate<2048>(hist, tid, r2, wsum, selres);
    uint va, vb;
    if (A1.x != A2.x) {
        // r1 is max of bin A1, r2 is min of bin A2
        if (tid == 0) { selres[0] = 0u; selres[1] = 0xFFFFFFFFu; }
        __syncthreads();
        for (int c = 0; c < ept; ++c) {
            uint k = key_at(sh, eb + tid + (c << 9));
            uint b = k >> 20;
            if (b == A1.x) atomicMax(&selres[0], k);
            if (b == A2.x) atomicMin(&selres[1], k);
        }
        __syncthreads();
        va = selres[0]; vb = selres[1];
        __syncthreads();
    } else {
        uint p1 = A1.x;
        // scan 2: bins = bits 19..9 filtered on coarse bin
        for (int k = tid; k < 2048; k += NT) hist[k] = 0u;
        __syncthreads();
        for (int c = 0; c < ept; ++c) {
            uint k = key_at(sh, eb + tid + (c << 9));
            if ((k >> 20) == p1) atomicAdd(&hist[(k >> 9) & 2047u], 1u);
        }
        __syncthreads();
        uint2 B1 = hist_locate<2048>(hist, tid, r1 - A1.y, wsum, selres);
        uint2 B2 = hist_locate<2048>(hist, tid, r2 - A1.y, wsum, selres);
        if (B1.x != B2.x) {
            uint pA = (p1 << 11) | B1.x, pB = (p1 << 11) | B2.x;
            if (tid == 0) { selres[0] = 0u; selres[1] = 0xFFFFFFFFu; }
            __syncthreads();
            for (int c = 0; c < ept; ++c) {
                uint k = key_at(sh, eb + tid + (c << 9));
                uint b = k >> 9;
                if (b == pA) atomicMax(&selres[0], k);
                if (b == pB) atomicMin(&selres[1], k);
            }
            __syncthreads();
            va = selres[0]; vb = selres[1];
            __syncthreads();
        } else {
            uint pfx = (p1 << 11) | B1.x;
            // scan 3: bins = bits 8..0 filtered; bins ARE exact low bits
            for (int k = tid; k < 512; k += NT) hist[k] = 0u;
            __syncthreads();
            for (int c = 0; c < ept; ++c) {
                uint k = key_at(sh, eb + tid + (c << 9));
                if ((k >> 9) == pfx) atomicAdd(&hist[k & 511u], 1u);
            }
            __syncthreads();
            uint2 C1 = hist_locate<512>(hist, tid, r1 - A1.y - B1.y, wsum, selres);
            uint2 C2 = hist_locate<512>(hist, tid, r2 - A1.y - B1.y, wsum, selres);
            va = (pfx << 9) | C1.x;
            vb = (pfx << 9) | C2.x;
        }
    }
    return 0.5f * (__uint_as_float(va) + __uint_as_float(vb));
}

// ---------------- frontier node filter -------------------------------------
__device__ void filter_node(
    float2* sh, int d, int n, int tid,
    const float* wsh, const float* sSe, const float* sCoh, const int* fP,
    uint* hist, uint* wsum, uint* selres,
    float lfg, float sigma, float hfg, float cutoff)
{
    int lognd = LOGN - d;
    int nd = 1 << lognd;
    int ept = nd >> 9;
    int g = (1 << d) - 1 + n;
    int eb = n << lognd;
    float bcv = (d == 0) ? 0.f : ((float)n + 0.5f) / (float)(1 << d);
    float coh = sCoh[g], sev = sSe[g];
    float nle = __logf(fmaxf(sev / (float)nd, EPSF));
    float dnv = (float)d * 0.25f;
    float lbb = 1.f + lfg * __expf(-(bcv * bcv) / (sigma * sigma));
    float hbd = hfg + (1.f - hfg) * fast_rcp(1.f + __expf(-(cutoff - bcv) / sigma));
    float gbase = lbb * hbd * (1.f + lfg * coh) * (hfg + (1.f - hfg) * coh);
    float invnm1 = 1.f / (float)(nd - 1);
    float w0r[12], w1r[12], w6r[12], wo0r[12], wo1r[12], hb[12];
    #pragma unroll
    for (int j = 0; j < 12; ++j) {
        w0r[j] = wsh[j * 7 + 0]; w1r[j] = wsh[j * 7 + 1]; w6r[j] = wsh[j * 7 + 6];
        wo0r[j] = wsh[96 + j]; wo1r[j] = wsh[108 + j];
        hb[j] = wsh[84 + j] + nle * wsh[j * 7 + 2] + dnv * wsh[j * 7 + 3]
              + bcv * wsh[j * 7 + 4] + coh * wsh[j * 7 + 5];
    }
    float bo0 = wsh[120], bo1 = wsh[121];

    for (int c = 0; c < ept; ++c) {
        int i = tid + (c << 9);
        int p = eb + i;
        float2 cv = sh[p];
        float m2 = cv.x * cv.x + cv.y * cv.y;
        float f0 = 0.5f * __logf(fmaxf(m2, 1e-12f));
        float f1 = fast_atan2f(cv.y, cv.x) * INV_PIF;
        float f6 = (float)i * invnm1;
        float acc0 = bo0, acc1 = bo1;
        #pragma unroll
        for (int j = 0; j < 12; ++j) {
            float h = fmaf(f0, w0r[j], fmaf(f1, w1r[j], fmaf(f6, w6r[j], hb[j])));
            float s = h * fast_rcp(1.f + __expf(-h));
            acc0 = fmaf(s, wo0r[j], acc0);
            acc1 = fmaf(s, wo1r[j], acc1);
        }
        float gm = gbase * __expf(0.25f * tanh_fast(acc0));
        float dph = HALF_PIF * tanh_fast(acc1);
        float sp = __sinf(dph), cp = __cosf(dph);
        float fr = gm * (cv.x * cp - cv.y * sp);
        float fi = gm * (cv.x * sp + cv.y * cp);
        sh[p] = make_float2(fr, fi);
    }
    __syncthreads();

    float nf = median_node(sh, eb, ept, nd, tid, hist, wsum, selres);
    float thr = (1.f - hbd) * nf;
    float pf = fP[g] ? (hfg * hfg) : 1.f;

    for (int c = 0; c < ept; ++c) {
        int p = eb + tid + (c << 9);
        float2 v = sh[p];
        float fm = sqrtf(v.x * v.x + v.y * v.y);
        float den = fmaxf(fm - thr, 0.f);
        float s = den * fast_rcp(fmaxf(fm, EPSF)) * pf;
        sh[p] = make_float2(v.x * s, v.y * s);
    }
    __syncthreads();
}

// ---------------- K2: decide + bottom-up apply + IFFT ----------------------
__global__ __launch_bounds__(NT, 4) void k_rest(
    const float2* __restrict__ Lv,
    const float* __restrict__ Se, const float* __restrict__ Coh, const float* __restrict__ Ent,
    float* __restrict__ out,
    const float* __restrict__ Wp, const float* __restrict__ bp,
    const float* __restrict__ Wo, const float* __restrict__ bo,
    const float* lfg_p, const float* sig_p, const float* hfg_p, const float* cut_p)
{
    __shared__ float2 sh[NN];                 // 64KB
    __shared__ __align__(16) uint hist[2048]; // 8KB
    __shared__ float wsh[122];
    __shared__ float sSe[NNODES], sCoh[NNODES];
    __shared__ int fF[NNODES], fP[NNODES];
    __shared__ float dtmp[3 * NNODES];
    __shared__ uint wsum[8];
    __shared__ uint selres[2];

    int row = blockIdx.x, tid = threadIdx.x;
    float lfg = *lfg_p, sigma = *sig_p, hfg = *hfg_p, cutoff = *cut_p;

    // issue leaves load early (completes under decide's compute)
    const float4* lrow = (const float4*)(Lv + ((size_t)row << LOGN));
    float4* s4 = (float4*)sh;
    #pragma unroll
    for (int t = 0; t < 8; ++t) { int k = tid + (t << 9); s4[k] = lrow[k]; }

    if (tid < 122) wsh[tid] = (tid < 84) ? Wp[tid] : (tid < 96) ? bp[tid - 84]
                            : (tid < 120) ? Wo[tid - 96] : bo[tid - 120];
    if (tid < NNODES) { sSe[tid] = Se[tid * ROWS + row]; sCoh[tid] = Coh[tid * ROWS + row]; }

    dev_decide(Se, Coh, Ent, tid, row, dtmp, fF, fP);   // barriers inside

    // depth-4 frontier leaves
    for (int n = 0; n < 16; ++n)
        if (fF[15 + n])
            filter_node(sh, 4, n, tid, wsh, sSe, sCoh, fP, hist, wsum, selres, lfg, sigma, hfg, cutoff);

    // bottom-up: merge all pairs at each level, then filter frontier nodes
    for (int d = 3; d >= 0; --d) {
        int lognd = LOGN - d;
        int half = 1 << (lognd - 1);
        float2 lo[8], hi[8];
        #pragma unroll
        for (int t = 0; t < 8; ++t) {
            int j = tid + (t << 9);
            int n = j >> (lognd - 1);
            int i = j & (half - 1);
            lo[t] = sh[(n << lognd) + i];
            hi[t] = sh[(n << lognd) + half + i];
        }
        __syncthreads();
        #pragma unroll
        for (int t = 0; t < 8; ++t) {
            int j = tid + (t << 9);
            int n = j >> (lognd - 1);
            int i = j & (half - 1);
            float4 w;
            w.x = (lo[t].x + hi[t].x) * SQRT1_2F; w.y = (lo[t].y + hi[t].y) * SQRT1_2F;
            w.z = (lo[t].x - hi[t].x) * SQRT1_2F; w.w = (lo[t].y - hi[t].y) * SQRT1_2F;
            *reinterpret_cast<float4*>(&sh[(n << lognd) + 2 * i]) = w;
        }
        __syncthreads();
        for (int n = 0; n < (1 << d); ++n)
            if (fF[(1 << d) - 1 + n])
                filter_node(sh, d, n, tid, wsh, sSe, sCoh, fP, hist, wsum, selres, lfg, sigma, hfg, cutoff);
    }

    // in-place bit-reverse + inverse FFT + real output
    #pragma unroll
    for (int t = 0; t < 16; ++t) {
        int p = tid + (t << 9);
        int r = __brev((uint)p) >> (32 - LOGN);
        if (p < r) { float2 a = sh[p], b = sh[r]; sh[p] = b; sh[r] = a; }
    }
    __syncthreads();
    fft_lds(sh, tid, +1.f);
    float* orow = out + ((size_t)row << LOGN);
    #pragma unroll
    for (int t = 0; t < 16; ++t) {
        int k = tid + (t << 9);
        orow[k] = sh[k].x * (1.0f / (float)NN);
    }
}

// ---------------- host launch ----------------------------------------------
extern "C" void kernel_launch(void* const* d_in, const int* in_sizes, int n_in,
                              void* d_out, int out_size, void* d_ws, size_t ws_size,
                              hipStream_t stream) {
    const float* x   = (const float*)d_in[0];
    const float* Wp  = (const float*)d_in[1];
    const float* bp  = (const float*)d_in[2];
    const float* Wo  = (const float*)d_in[3];
    const float* bo  = (const float*)d_in[4];
    const float* lfg = (const float*)d_in[5];
    const float* sig = (const float*)d_in[6];
    const float* hfg = (const float*)d_in[7];
    const float* cut = (const float*)d_in[8];
    float* out = (float*)d_out;

    size_t S = (size_t)ROWS * NN * sizeof(float2);   // 33,554,432 B
    char* ws = (char*)d_ws;
    float2* Lv = (float2*)ws;
    float*  Se  = (float*)(ws + S);
    float*  Coh = Se  + (size_t)NNODES * ROWS;
    float*  Ent = Coh + (size_t)NNODES * ROWS;
    size_t need = (size_t)((char*)(Ent + (size_t)NNODES * ROWS) - ws);
    if (ws_size < need) return;

    dim3 b(NT);
    k_pre <<<dim3(ROWS), b, 0, stream>>>(x, Lv, Se, Coh, Ent, lfg, sig, hfg, cut);
    k_rest<<<dim3(ROWS), b, 0, stream>>>(Lv, Se, Coh, Ent, out, Wp, bp, Wo, bo, lfg, sig, hfg, cut);
}

// Round 6
// 138.154 us; speedup vs baseline: 7.0800x; 1.2262x over previous
//
#include <hip/hip_runtime.h>
#include <math.h>

#define NN      8192
#define LOGN    13
#define ROWS    512
#define NT      512
#define NNODES  31
#define EPSF    1e-6f
#define PRUNEF  0.05f
#define SQRT1_2F 0.70710678118654752f
#define PIF      3.14159265358979323f
#define INV_PIF  0.31830988618379067f
#define HALF_PIF 1.57079632679489662f

typedef unsigned int uint;

// ---------------- fast math ----------------
__device__ __forceinline__ float fast_rcp(float x){ return __builtin_amdgcn_rcpf(x); }
__device__ __forceinline__ float fast_rsq(float x){ return __builtin_amdgcn_rsqf(x); }

__device__ __forceinline__ float tanh_fast(float x){
    float e = __expf(2.f * x);
    return 1.f - 2.f * fast_rcp(e + 1.f);
}
// silu via Pade[3/4] tanh(h/2); poly + 1 rcp, no trans
__device__ __forceinline__ float silu_pade(float h){
    float y = fminf(3.f, fmaxf(-3.f, 0.5f * h));
    float y2 = y * y;
    float num = y * fmaf(y2, 10.f, 105.f);
    float den = fmaf(y2, 45.f, fmaf(y2 * y2, 1.f, 105.f));
    return 0.5f * h * (1.f + num * fast_rcp(den));
}
// exp(z) for |z|<=0.26
__device__ __forceinline__ float exp_small(float z){
    return fmaf(z, fmaf(z, fmaf(z, fmaf(z, 0.041666667f, 0.16666667f), 0.5f), 1.f), 1.f);
}

__device__ __forceinline__ float fast_atan2f(float y, float x) {
    float ay = fabsf(y), ax = fabsf(x);
    float mx = fmaxf(ax, ay), mn = fminf(ax, ay);
    float a = (mx > 0.f) ? (mn * fast_rcp(mx)) : 0.f;
    bool big = a > 0.4142135679f;
    float t = big ? ((a - 1.f) * fast_rcp(a + 1.f)) : a;
    float z2 = t * t;
    float p = fmaf(8.05374449538e-2f, z2, -1.38776856032e-1f);
    p = fmaf(p, z2, 1.99777106478e-1f);
    p = fmaf(p, z2, -3.33329491539e-1f);
    float r = fmaf(p * z2, t, t);
    if (big) r += 0.78539816339744831f;
    if (ay > ax) r = 1.57079632679489662f - r;
    if (x < 0.f) r = 3.14159265358979323f - r;
    return copysignf(r, y);
}

__device__ __forceinline__ float2 cmul(float2 a, float2 b){
    return make_float2(a.x*b.x - a.y*b.y, a.x*b.y + a.y*b.x);
}
__device__ __forceinline__ float2 cadd(float2 a, float2 b){ return make_float2(a.x+b.x, a.y+b.y); }
__device__ __forceinline__ float2 csub(float2 a, float2 b){ return make_float2(a.x-b.x, a.y-b.y); }

__device__ __forceinline__ void wave_red8(float* a) {
    #pragma unroll
    for (int m = 32; m >= 1; m >>= 1) {
        #pragma unroll
        for (int q = 0; q < 8; ++q) a[q] += __shfl_xor(a[q], m);
    }
}

// ======================= K1: FFT + filter + stats pyramid ==================
// Output leaves in bit-reversed spectral domain. LDS ~64.5KB -> 2 blocks/CU.
__global__ __launch_bounds__(NT, 4) void k_pre(
    const float* __restrict__ x, float2* __restrict__ Lv,
    float* __restrict__ Se, float* __restrict__ Coh, float* __restrict__ Ent,
    const float* lfg_p, const float* sig_p, const float* hfg_p, const float* cut_p)
{
    __shared__ float2 sh[NN];        // 64KB (bit-rev spectral domain)
    __shared__ float4 wred[8];
    __shared__ float nacc[16][4];
    int row = blockIdx.x, tid = threadIdx.x;
    float lfg = *lfg_p, sigma = *sig_p, hfg = *hfg_p, cutoff = *cut_p;

    // ---- load natural order ----
    const float* xr = x + ((size_t)row << LOGN);
    #pragma unroll
    for (int t = 0; t < 16; ++t) {
        int i = tid + (t << 9);
        sh[i] = make_float2(xr[i], 0.f);
    }
    __syncthreads();

    // ---- forward DIF radix-4 FFT (natural in -> bit-rev out) ----
    for (int sp = 0; sp < 6; ++sp) {
        int lg = 11 - 2 * sp;
        int Hh = 1 << lg;
        float angf = -PIF / (float)(2 * Hh);
        #pragma unroll 4
        for (int c = 0; c < 4; ++c) {
            int q = tid + (c << 9);
            int j = q & (Hh - 1);
            int p = ((q >> lg) << (lg + 2)) | j;
            float2 a = sh[p], b = sh[p + Hh], cc = sh[p + 2 * Hh], d = sh[p + 3 * Hh];
            float ang = angf * (float)j;
            float s = __sinf(ang), co = __cosf(ang);
            float2 t1 = make_float2(co, s);
            float2 t2 = make_float2(co * co - s * s, 2.f * co * s);
            float2 a1 = cadd(a, cc);
            float2 c1 = cmul(csub(a, cc), t1);
            float2 b1 = cadd(b, d);
            float2 u  = cmul(csub(b, d), t1);
            float2 d1 = make_float2(u.y, -u.x);          // -i*u
            sh[p]          = cadd(a1, b1);
            sh[p + Hh]     = cmul(csub(a1, b1), t2);
            sh[p + 2 * Hh] = cadd(c1, d1);
            sh[p + 3 * Hh] = cmul(csub(c1, d1), t2);
        }
        __syncthreads();
    }
    #pragma unroll 8
    for (int c = 0; c < 8; ++c) {                        // tail radix-2 (len 2)
        int p = (tid + (c << 9)) << 1;
        float2 a = sh[p], b = sh[p + 1];
        sh[p] = cadd(a, b);
        sh[p + 1] = csub(a, b);
    }
    __syncthreads();

    // ---- frequency filter + root stats ----
    float inv_gs = 1.f / fmaxf(sigma, 0.05f);
    float is2 = 1.f / (sigma * sigma);
    float se = 0.f, slg = 0.f, sux = 0.f, suy = 0.f;
    #pragma unroll
    for (int t = 0; t < 16; ++t) {
        int p = tid + (t << 9);
        int k = (int)(__brev((uint)p) >> 19);            // true frequency index
        float fk = (k < NN / 2) ? (float)k : (float)(k - NN);
        float f = fk * (1.0f / (float)NN);
        float r2 = f * f;
        float lfb = 1.f + lfg * __expf(-r2 * is2);
        float radius = sqrtf(r2 + 1e-12f);
        float gate = fast_rcp(1.f + __expf(-(cutoff - radius) * inv_gs));
        float mult = lfb * (hfg + (1.f - hfg) * gate);
        float2 c = sh[p];
        c.x *= mult; c.y *= mult;
        sh[p] = c;
        float e = fmaf(c.x, c.x, c.y * c.y);
        se += e;
        slg += e * __logf(fmaxf(e, 1e-30f));
        float inv = fminf(fast_rsq(e), 1e6f);
        sux += c.x * inv; suy += c.y * inv;
    }
    #pragma unroll
    for (int m = 32; m >= 1; m >>= 1) {
        se += __shfl_xor(se, m); slg += __shfl_xor(slg, m);
        sux += __shfl_xor(sux, m); suy += __shfl_xor(suy, m);
    }
    if ((tid & 63) == 0) wred[tid >> 6] = make_float4(se, slg, sux, suy);
    __syncthreads();
    if (tid == 0) {
        float4 r = wred[0];
        #pragma unroll
        for (int w = 1; w < 8; ++w) {
            r.x += wred[w].x; r.y += wred[w].y; r.z += wred[w].z; r.w += wred[w].w;
        }
        float gx = r.z / (float)NN, gy = r.w / (float)NN;
        float ga = sqrtf(gx * gx + gy * gy);
        float denom = fmaxf(r.x, EPSF);
        Se[row]  = r.x;
        Ent[row] = __logf(denom) - r.y / denom;
        Coh[row] = fminf(ga, 1.f);       // |mean(unit)*conj(gpu)| == |mean(unit)|
    }

    // ---- stats pyramid: in-place stride butterflies (bit-rev domain) ----
    for (int dp = 0; dp < 4; ++dp) {
        int shn = 12 - dp;
        int h = 1 << shn;
        int fim1 = (1 << (3 - dp)) - 1;
        if (tid < 64) ((float*)nacc)[tid] = 0.f;
        __syncthreads();
        float acc[8] = {0,0,0,0,0,0,0,0};
        #pragma unroll
        for (int t = 0; t < 8; ++t) {
            int q = tid + (t << 9);
            int p = ((q & ~(h - 1)) << 1) | (q & (h - 1));
            float2 a = sh[p], b = sh[p + h];
            float2 lo = make_float2((a.x + b.x) * SQRT1_2F, (a.y + b.y) * SQRT1_2F);
            float2 hi = make_float2((a.x - b.x) * SQRT1_2F, (a.y - b.y) * SQRT1_2F);
            sh[p] = lo; sh[p + h] = hi;
            float e1 = fmaf(lo.x, lo.x, lo.y * lo.y);
            acc[0] += e1; acc[1] += e1 * __logf(fmaxf(e1, 1e-30f));
            float i1 = fminf(fast_rsq(e1), 1e6f);
            acc[2] += lo.x * i1; acc[3] += lo.y * i1;
            float e2 = fmaf(hi.x, hi.x, hi.y * hi.y);
            acc[4] += e2; acc[5] += e2 * __logf(fmaxf(e2, 1e-30f));
            float i2 = fminf(fast_rsq(e2), 1e6f);
            acc[6] += hi.x * i2; acc[7] += hi.y * i2;
            if (((t + 1) & fim1) == 0) {
                wave_red8(acc);
                if ((tid & 63) == 0) {
                    int ca = (q >> shn) << 1;
                    atomicAdd(&nacc[ca][0], acc[0]);   atomicAdd(&nacc[ca][1], acc[1]);
                    atomicAdd(&nacc[ca][2], acc[2]);   atomicAdd(&nacc[ca][3], acc[3]);
                    atomicAdd(&nacc[ca+1][0], acc[4]); atomicAdd(&nacc[ca+1][1], acc[5]);
                    atomicAdd(&nacc[ca+1][2], acc[6]); atomicAdd(&nacc[ca+1][3], acc[7]);
                }
                #pragma unroll
                for (int qq = 0; qq < 8; ++qq) acc[qq] = 0.f;
            }
        }
        __syncthreads();
        int cn = 2 << dp;
        if (tid < cn) {
            float E = nacc[tid][0], SL = nacc[tid][1], ZX = nacc[tid][2], ZY = nacc[tid][3];
            float denom = fmaxf(E, EPSF);
            float ent = __logf(denom) - SL / denom;
            float invn = 1.f / (float)(1 << shn);
            float zx = ZX * invn, zy = ZY * invn;
            float ch = fminf(sqrtf(zx * zx + zy * zy), 1.f);
            int g = cn - 1 + tid;
            Se[g * ROWS + row] = E; Coh[g * ROWS + row] = ch; Ent[g * ROWS + row] = ent;
        }
        __syncthreads();
    }

    // ---- store depth-4 leaves (bit-rev domain), coalesced float4 ----
    float4* lrow = (float4*)(Lv + ((size_t)row << LOGN));
    const float4* s4 = (const float4*)sh;
    #pragma unroll
    for (int t = 0; t < 8; ++t) { int k = tid + (t << 9); lrow[k] = s4[k]; }
}

// ======================= median select (1024-bin, m^2 keys) ================
__device__ __forceinline__ uint key_at(const float2* sh, int p) {
    float2 v = sh[p];
    return __float_as_uint(fmaf(v.x, v.x, v.y * v.y));
}

__device__ __forceinline__ uint2 hist_locate1024(
    const uint* hist, int tid, uint r, uint* wsum, uint* selres)
{
    uint l0 = hist[2 * tid], l1 = hist[2 * tid + 1];
    uint s = l0 + l1;
    uint sc = s;
    #pragma unroll
    for (int o = 1; o < 64; o <<= 1) {
        uint v = __shfl_up(sc, o);
        if ((tid & 63) >= o) sc += v;
    }
    int wid = tid >> 6;
    if ((tid & 63) == 63) wsum[wid] = sc;
    __syncthreads();
    uint wb = 0;
    #pragma unroll
    for (int w = 0; w < 8; ++w) if (w < wid) wb += wsum[w];
    uint c0 = wb + sc - s;
    if (r >= c0 && r < c0 + l0) { selres[0] = 2u * tid;      selres[1] = c0; }
    c0 += l0;
    if (r >= c0 && r < c0 + l1) { selres[0] = 2u * tid + 1u; selres[1] = c0; }
    __syncthreads();
    uint2 res = make_uint2(selres[0], selres[1]);
    __syncthreads();
    return res;
}

// exact-to-1ulp median of |filtered| over the node segment; 3 scans typical
__device__ float median_node(
    const float2* sh, int eb, int ept, int nd, int tid,
    uint* hist, uint* wsum, uint* selres)
{
    uint r1 = (uint)(nd / 2 - 1), r2 = (uint)(nd / 2);
    // pass 1: bins = key bits 30..21
    for (int k = tid; k < 1024; k += NT) hist[k] = 0u;
    __syncthreads();
    for (int c = 0; c < ept; ++c)
        atomicAdd(&hist[key_at(sh, eb + tid + (c << 9)) >> 21], 1u);
    __syncthreads();
    uint2 A1 = hist_locate1024(hist, tid, r1, wsum, selres);
    uint2 A2 = hist_locate1024(hist, tid, r2, wsum, selres);
    uint va, vb;
    if (A1.x != A2.x) {
        if (tid == 0) { selres[0] = 0u; selres[1] = 0xFFFFFFFFu; }
        __syncthreads();
        for (int c = 0; c < ept; ++c) {
            uint k = key_at(sh, eb + tid + (c << 9));
            uint b = k >> 21;
            if (b == A1.x) atomicMax(&selres[0], k);
            if (b == A2.x) atomicMin(&selres[1], k);
        }
        __syncthreads();
        va = selres[0]; vb = selres[1];
        __syncthreads();
    } else {
        uint p1 = A1.x;
        // pass 2: bins = bits 20..11, filtered on pass-1 bin
        for (int k = tid; k < 1024; k += NT) hist[k] = 0u;
        __syncthreads();
        for (int c = 0; c < ept; ++c) {
            uint k = key_at(sh, eb + tid + (c << 9));
            if ((k >> 21) == p1) atomicAdd(&hist[(k >> 11) & 1023u], 1u);
        }
        __syncthreads();
        uint2 B1 = hist_locate1024(hist, tid, r1 - A1.y, wsum, selres);
        uint2 B2 = hist_locate1024(hist, tid, r2 - A1.y, wsum, selres);
        if (B1.x != B2.x) {
            uint pA = (p1 << 10) | B1.x, pB = (p1 << 10) | B2.x;
            if (tid == 0) { selres[0] = 0u; selres[1] = 0xFFFFFFFFu; }
            __syncthreads();
            for (int c = 0; c < ept; ++c) {
                uint k = key_at(sh, eb + tid + (c << 9));
                uint b = k >> 11;
                if (b == pA) atomicMax(&selres[0], k);
                if (b == pB) atomicMin(&selres[1], k);
            }
            __syncthreads();
            va = selres[0]; vb = selres[1];
            __syncthreads();
        } else {
            uint pfx = (p1 << 10) | B1.x;
            // pass 3: bins = bits 10..1 (bit 0 truncated: <=1 ulp of m^2)
            for (int k = tid; k < 1024; k += NT) hist[k] = 0u;
            __syncthreads();
            for (int c = 0; c < ept; ++c) {
                uint k = key_at(sh, eb + tid + (c << 9));
                if ((k >> 11) == pfx) atomicAdd(&hist[(k >> 1) & 1023u], 1u);
            }
            __syncthreads();
            uint2 C1 = hist_locate1024(hist, tid, r1 - A1.y - B1.y, wsum, selres);
            uint2 C2 = hist_locate1024(hist, tid, r2 - A1.y - B1.y, wsum, selres);
            va = ((pfx << 10) | C1.x) << 1;
            vb = ((pfx << 10) | C2.x) << 1;
        }
    }
    return 0.5f * (sqrtf(__uint_as_float(va)) + sqrtf(__uint_as_float(vb)));
}

// ---------------- per-block redundant decide -------------------------------
__device__ __forceinline__ void dev_decide(
    const float* __restrict__ Se, const float* __restrict__ Coh, const float* __restrict__ Ent,
    int tid, float* dtmp, int* fF, int* fP)
{
    float* dcost = dtmp; float* dne = dtmp + NNODES; float* dcm = dtmp + 2 * NNODES;
    int wid = tid >> 6, lane = tid & 63;
    for (int gn = wid; gn < NNODES; gn += 8) {
        float a = 0.f, b = 0.f, cc = 0.f;
        #pragma unroll
        for (int rr = 0; rr < ROWS / 64; ++rr) {
            int r = lane + (rr << 6);
            float ch = Coh[gn * ROWS + r];
            a += Ent[gn * ROWS + r] + 1.f - ch;
            b += Se[gn * ROWS + r];
            cc += ch;
        }
        #pragma unroll
        for (int m = 32; m >= 1; m >>= 1) {
            a += __shfl_xor(a, m); b += __shfl_xor(b, m); cc += __shfl_xor(cc, m);
        }
        if (lane == 0) { dcost[gn] = a / (float)ROWS; dne[gn] = b; dcm[gn] = cc / (float)ROWS; }
    }
    __syncthreads();
    if (tid == 0) {
        float mc[NNODES]; int sel[NNODES]; int act[NNODES];
        for (int gn = NNODES - 1; gn >= 0; --gn) {
            if (gn >= 15) { mc[gn] = dcost[gn]; sel[gn] = 0; }
            else {
                float chc = mc[2 * gn + 1] + mc[2 * gn + 2];
                sel[gn] = (chc < dcost[gn]) ? 1 : 0;
                mc[gn] = fminf(chc, dcost[gn]);
            }
        }
        float total_e = dne[0];
        act[0] = 1;
        for (int gn = 1; gn < NNODES; ++gn) {
            int p = (gn - 1) >> 1;
            act[gn] = act[p] && sel[p];
        }
        for (int gn = 0; gn < NNODES; ++gn) {
            int isleaf = (gn >= 15);
            fF[gn] = (act[gn] && (isleaf || !sel[gn])) ? 1 : 0;
            fP[gn] = ((dne[gn] / total_e < PRUNEF) || (dcm[gn] < PRUNEF)) ? 1 : 0;
        }
    }
    __syncthreads();
}

// ---------------- frontier node filter (bit-rev domain) --------------------
__device__ void filter_node(
    float2* sh, int d, int n, int tid,
    const float* wsh, const float* sSe, const float* sCoh, const int* fP,
    uint* hist, uint* wsum, uint* selres,
    float lfg, float sigma, float hfg, float cutoff)
{
    int lognd = LOGN - d;
    int nd = 1 << lognd;
    int ept = nd >> 9;
    int g = (1 << d) - 1 + n;
    int eb = n << lognd;
    float bcv = (d == 0) ? 0.f : ((float)n + 0.5f) / (float)(1 << d);
    float coh = sCoh[g], sev = sSe[g];
    float nle = __logf(fmaxf(sev / (float)nd, EPSF));
    float dnv = (float)d * 0.25f;
    float lbb = 1.f + lfg * __expf(-(bcv * bcv) / (sigma * sigma));
    float hbd = hfg + (1.f - hfg) * fast_rcp(1.f + __expf(-(cutoff - bcv) / sigma));
    float gbase = lbb * hbd * (1.f + lfg * coh) * (hfg + (1.f - hfg) * coh);
    float invnm1 = 1.f / (float)(nd - 1);
    float w0r[12], w1r[12], w6r[12], wo0r[12], wo1r[12], hb[12];
    #pragma unroll
    for (int j = 0; j < 12; ++j) {
        w0r[j] = wsh[j*7+0]; w1r[j] = wsh[j*7+1]; w6r[j] = wsh[j*7+6];
        wo0r[j] = wsh[96+j]; wo1r[j] = wsh[108+j];
        hb[j] = wsh[84+j] + nle*wsh[j*7+2] + dnv*wsh[j*7+3] + bcv*wsh[j*7+4] + coh*wsh[j*7+5];
    }
    float bo0 = wsh[120], bo1 = wsh[121];

    for (int c = 0; c < ept; ++c) {
        int o = tid + (c << 9);
        int p = eb + o;
        float2 cv = sh[p];
        float m2 = fmaf(cv.x, cv.x, cv.y * cv.y);
        float f0 = 0.5f * __logf(fmaxf(m2, 1e-12f));
        float f1 = fast_atan2f(cv.y, cv.x) * INV_PIF;
        int itrue = (int)(__brev((uint)o) >> (19 + d));   // true in-node index
        float f6 = (float)itrue * invnm1;
        float acc0 = bo0, acc1 = bo1;
        #pragma unroll
        for (int j = 0; j < 12; ++j) {
            float h = fmaf(f0, w0r[j], fmaf(f1, w1r[j], fmaf(f6, w6r[j], hb[j])));
            float s = silu_pade(h);
            acc0 = fmaf(s, wo0r[j], acc0);
            acc1 = fmaf(s, wo1r[j], acc1);
        }
        float gm = gbase * exp_small(0.25f * tanh_fast(acc0));
        float dph = HALF_PIF * tanh_fast(acc1);
        float spv, cpv;
        __sincosf(dph, &spv, &cpv);
        float fr = gm * (cv.x * cpv - cv.y * spv);
        float fi = gm * (cv.x * spv + cv.y * cpv);
        sh[p] = make_float2(fr, fi);
    }
    __syncthreads();

    float nf = median_node(sh, eb, ept, nd, tid, hist, wsum, selres);
    float thr = (1.f - hbd) * nf;
    float pf = fP[g] ? (hfg * hfg) : 1.f;

    for (int c = 0; c < ept; ++c) {
        int p = eb + tid + (c << 9);
        float2 v = sh[p];
        float fm = sqrtf(fmaf(v.x, v.x, v.y * v.y));
        float den = fmaxf(fm - thr, 0.f);
        float s = den * fast_rcp(fmaxf(fm, EPSF)) * pf;
        sh[p] = make_float2(v.x * s, v.y * s);
    }
    __syncthreads();
}

// ======================= K2: decide + apply + inverse FFT ==================
__global__ __launch_bounds__(NT, 4) void k_rest(
    const float2* __restrict__ Lv,
    const float* __restrict__ Se, const float* __restrict__ Coh, const float* __restrict__ Ent,
    float* __restrict__ out,
    const float* __restrict__ Wp, const float* __restrict__ bp,
    const float* __restrict__ Wo, const float* __restrict__ bo,
    const float* lfg_p, const float* sig_p, const float* hfg_p, const float* cut_p)
{
    __shared__ float2 sh[NN];                   // 64KB
    __shared__ __align__(16) uint hist[1024];   // 4KB
    __shared__ float wsh[122];
    __shared__ float sSe[NNODES], sCoh[NNODES];
    __shared__ int fF[NNODES], fP[NNODES];
    __shared__ float dtmp[3 * NNODES];
    __shared__ uint wsum[8];
    __shared__ uint selres[2];

    int row = blockIdx.x, tid = threadIdx.x;
    float lfg = *lfg_p, sigma = *sig_p, hfg = *hfg_p, cutoff = *cut_p;

    // issue leaf load early; decide's compute covers the latency
    const float4* lrow = (const float4*)(Lv + ((size_t)row << LOGN));
    float4* s4 = (float4*)sh;
    #pragma unroll
    for (int t = 0; t < 8; ++t) { int k = tid + (t << 9); s4[k] = lrow[k]; }

    if (tid < 122) wsh[tid] = (tid < 84) ? Wp[tid] : (tid < 96) ? bp[tid - 84]
                            : (tid < 120) ? Wo[tid - 96] : bo[tid - 120];
    if (tid < NNODES) { sSe[tid] = Se[tid * ROWS + row]; sCoh[tid] = Coh[tid * ROWS + row]; }

    dev_decide(Se, Coh, Ent, tid, dtmp, fF, fP);        // barriers inside

    // depth-4 frontier leaves
    for (int n = 0; n < 16; ++n)
        if (fF[15 + n])
            filter_node(sh, 4, n, tid, wsh, sSe, sCoh, fP, hist, wsum, selres, lfg, sigma, hfg, cutoff);

    // bottom-up: merge all pairs per level (stride butterfly), filter frontier
    for (int d = 3; d >= 0; --d) {
        int h = 1 << (12 - d);
        #pragma unroll
        for (int t = 0; t < 8; ++t) {
            int q = tid + (t << 9);
            int p = ((q & ~(h - 1)) << 1) | (q & (h - 1));
            float2 lo = sh[p], hi = sh[p + h];
            sh[p]     = make_float2((lo.x + hi.x) * SQRT1_2F, (lo.y + hi.y) * SQRT1_2F);
            sh[p + h] = make_float2((lo.x - hi.x) * SQRT1_2F, (lo.y - hi.y) * SQRT1_2F);
        }
        __syncthreads();
        for (int n = 0; n < (1 << d); ++n)
            if (fF[(1 << d) - 1 + n])
                filter_node(sh, d, n, tid, wsh, sSe, sCoh, fP, hist, wsum, selres, lfg, sigma, hfg, cutoff);
    }

    // ---- inverse DIT radix-4 FFT (bit-rev in -> natural out) ----
    for (int sp = 0; sp < 6; ++sp) {
        int h = 1 << (2 * sp);
        float angf = PIF / (float)(2 * h);
        #pragma unroll 4
        for (int c = 0; c < 4; ++c) {
            int q = tid + (c << 9);
            int jj = q & (h - 1);
            int p0 = ((q >> (2 * sp)) << (2 * sp + 2)) | jj;
            float ang = angf * (float)jj;
            float s2 = __sinf(ang), c2 = __cosf(ang);
            float2 t2 = make_float2(c2, s2);
            float2 t1 = make_float2(c2 * c2 - s2 * s2, 2.f * c2 * s2);
            float2 a = sh[p0], b = sh[p0 + h], cc = sh[p0 + 2 * h], d = sh[p0 + 3 * h];
            float2 tb = cmul(t1, b);
            float2 ap = cadd(a, tb), bp2 = csub(a, tb);
            float2 td = cmul(t1, d);
            float2 cp = cadd(cc, td), dp2 = csub(cc, td);
            float2 tc = cmul(t2, cp);
            float2 u  = cmul(t2, dp2);
            float2 iB = make_float2(-u.y, u.x);          // +i*u
            sh[p0]         = cadd(ap, tc);
            sh[p0 + h]     = cadd(bp2, iB);
            sh[p0 + 2 * h] = csub(ap, tc);
            sh[p0 + 3 * h] = csub(bp2, iB);
        }
        __syncthreads();
    }
    {   // tail radix-2 (h = 4096) with twiddles
        float angf = PIF / 4096.f;
        #pragma unroll 8
        for (int c = 0; c < 8; ++c) {
            int p = tid + (c << 9);
            float ang = angf * (float)p;
            float s = __sinf(ang), co = __cosf(ang);
            float2 a = sh[p], b = sh[p + 4096];
            float2 tb = cmul(make_float2(co, s), b);
            sh[p] = cadd(a, tb);
            sh[p + 4096] = csub(a, tb);
        }
        __syncthreads();
    }
    float* orow = out + ((size_t)row << LOGN);
    #pragma unroll
    for (int t = 0; t < 16; ++t) {
        int i = tid + (t << 9);
        orow[i] = sh[i].x * (1.0f / (float)NN);
    }
}

// ---------------- host launch ----------------------------------------------
extern "C" void kernel_launch(void* const* d_in, const int* in_sizes, int n_in,
                              void* d_out, int out_size, void* d_ws, size_t ws_size,
                              hipStream_t stream) {
    const float* x   = (const float*)d_in[0];
    const float* Wp  = (const float*)d_in[1];
    const float* bp  = (const float*)d_in[2];
    const float* Wo  = (const float*)d_in[3];
    const float* bo  = (const float*)d_in[4];
    const float* lfg = (const float*)d_in[5];
    const float* sig = (const float*)d_in[6];
    const float* hfg = (const float*)d_in[7];
    const float* cut = (const float*)d_in[8];
    float* out = (float*)d_out;

    size_t S = (size_t)ROWS * NN * sizeof(float2);   // 33,554,432 B
    char* ws = (char*)d_ws;
    float2* Lv = (float2*)ws;
    float*  Se  = (float*)(ws + S);
    float*  Coh = Se  + (size_t)NNODES * ROWS;
    float*  Ent = Coh + (size_t)NNODES * ROWS;
    size_t need = (size_t)((char*)(Ent + (size_t)NNODES * ROWS) - ws);
    if (ws_size < need) return;

    dim3 b(NT);
    k_pre <<<dim3(ROWS), b, 0, stream>>>(x, Lv, Se, Coh, Ent, lfg, sig, hfg, cut);
    k_rest<<<dim3(ROWS), b, 0, stream>>>(Lv, Se, Coh, Ent, out, Wp, bp, Wo, bo, lfg, sig, hfg, cut);
}